// Round 9
// baseline (321.317 us; speedup 1.0000x reference)
//
#include <hip/hip_runtime.h>
#include <hip/hip_cooperative_groups.h>
#include <math.h>

namespace cg = cooperative_groups;

#define NN   8192
#define DIM  128
#define NE   262144
#define XB   128          // xtx units (64 rows each)
#define HB   256          // histogram chunks
#define EPB  (NE / HB)    // 1024 edges per chunk
#define RWB  32           // rows per GEMM unit (4 per thread)
#define BK   16           // k-chunk rows of W/M staged in LDS
#define SMEMF (64 * DIM + 64)   // 8256 floats = 33 KB

// bf16 via explicit bit math (this ROCm's __hip_bfloat16 lacks .data)
static __device__ __forceinline__ unsigned short f2bf(float f) {
  unsigned int u = __float_as_uint(f);
  return (unsigned short)((u + 0x7FFFu + ((u >> 16) & 1u)) >> 16);   // RNE
}
static __device__ __forceinline__ float bf2f(unsigned short h) {
  return __uint_as_float((unsigned int)h << 16);
}

// ==================== phase unit functions (block-scoped) ====================

// xtx unit u: stage 64 rows, write rinv for them, emit Mpart[u]
static __device__ void ph_xtx(int u, int tid, float* smem,
    const float* __restrict__ x, float* __restrict__ rinv,
    float* __restrict__ Mpart) {
  float* xs  = smem;
  float* rvs = smem + 64 * DIM;
  int row0 = u * 64;
  const float4* xsrc = (const float4*)(x + (size_t)row0 * DIM);
  float4* xdst = (float4*)xs;
  #pragma unroll
  for (int i = 0; i < 8; ++i) xdst[tid + 256 * i] = xsrc[tid + 256 * i];
  __syncthreads();
  int rr = tid >> 2, q = tid & 3;
  const float4* xr = (const float4*)&xs[rr * DIM + q * 32];
  float ss = 0.f;
  #pragma unroll
  for (int i = 0; i < 8; ++i) {
    float4 v = xr[i];
    ss += v.x * v.x + v.y * v.y + v.z * v.z + v.w * v.w;
  }
  ss += __shfl_xor(ss, 1);
  ss += __shfl_xor(ss, 2);
  if (q == 0) { float rv = 1.0f / sqrtf(ss); rvs[rr] = rv; rinv[row0 + rr] = rv; }
  __syncthreads();

  int ty = tid >> 4, tx = tid & 15;
  float acc[8][8];
  #pragma unroll
  for (int i = 0; i < 8; ++i)
    #pragma unroll
    for (int j = 0; j < 8; ++j) acc[i][j] = 0.f;
  #pragma unroll 2
  for (int r = 0; r < 64; ++r) {
    float4 a0 = *(const float4*)&xs[r * DIM + ty * 8];
    float4 a1 = *(const float4*)&xs[r * DIM + ty * 8 + 4];
    float4 b0 = *(const float4*)&xs[r * DIM + tx * 8];
    float4 b1 = *(const float4*)&xs[r * DIM + tx * 8 + 4];
    float rv = rvs[r];
    float a[8] = {a0.x * rv, a0.y * rv, a0.z * rv, a0.w * rv,
                  a1.x * rv, a1.y * rv, a1.z * rv, a1.w * rv};
    float b[8] = {b0.x, b0.y, b0.z, b0.w, b1.x, b1.y, b1.z, b1.w};
    #pragma unroll
    for (int i = 0; i < 8; ++i)
      #pragma unroll
      for (int j = 0; j < 8; ++j) acc[i][j] += a[i] * b[j];
  }
  float* o = Mpart + (size_t)u * (DIM * DIM);
  #pragma unroll
  for (int i = 0; i < 8; ++i) {
    *(float4*)&o[(ty * 8 + i) * DIM + tx * 8]     = make_float4(acc[i][0], acc[i][1], acc[i][2], acc[i][3]);
    *(float4*)&o[(ty * 8 + i) * DIM + tx * 8 + 4] = make_float4(acc[i][4], acc[i][5], acc[i][6], acc[i][7]);
  }
}

// hist chunk h: LDS histogram; 1 global atomic per TOUCHED bin gives the
// chunk's bin base; per-edge final slot = base + local rank.
static __device__ void ph_hist(int h, int tid, int* ldeg,
    const int* __restrict__ ei, int* __restrict__ gcnt, int* __restrict__ slot) {
  int4* lz = (int4*)ldeg;
  #pragma unroll
  for (int i = tid; i < NN / 4; i += 256) lz[i] = make_int4(0, 0, 0, 0);
  __syncthreads();
  int e0 = h * EPB + tid * 4;
  int4 c = *(const int4*)(ei + NE + e0);      // targets
  int r0 = atomicAdd(&ldeg[c.x], 1);
  int r1 = atomicAdd(&ldeg[c.y], 1);
  int r2 = atomicAdd(&ldeg[c.z], 1);
  int r3 = atomicAdd(&ldeg[c.w], 1);
  __syncthreads();
  int binb = tid * 32;
  #pragma unroll
  for (int i = 0; i < 8; ++i) {
    int4 v = *(int4*)&ldeg[binb + i * 4];
    if (v.x) ldeg[binb + i * 4 + 0] = atomicAdd(&gcnt[binb + i * 4 + 0], v.x);
    if (v.y) ldeg[binb + i * 4 + 1] = atomicAdd(&gcnt[binb + i * 4 + 1], v.y);
    if (v.z) ldeg[binb + i * 4 + 2] = atomicAdd(&gcnt[binb + i * 4 + 2], v.z);
    if (v.w) ldeg[binb + i * 4 + 3] = atomicAdd(&gcnt[binb + i * 4 + 3], v.w);
  }
  __syncthreads();
  int4 sl;
  sl.x = ldeg[c.x] + r0;
  sl.y = ldeg[c.y] + r1;
  sl.z = ldeg[c.z] + r2;
  sl.w = ldeg[c.w] + r3;
  *(int4*)(slot + e0) = sl;
}

// M-reduce unit u: sum 128 partials for 64 entries, 4-way split-K via LDS
static __device__ void ph_mred(int u, int tid, float* smem,
    const float* __restrict__ Mpart, float* __restrict__ Mmat) {
  int j0 = u * 64;
  int jj = tid & 63, sub = tid >> 6;
  const float* mp = Mpart + (size_t)(sub * 32) * (DIM * DIM) + j0;
  float s = 0.f;
  #pragma unroll 4
  for (int k = 0; k < 32; ++k) s += mp[(size_t)k * (DIM * DIM) + jj];
  smem[sub * 64 + jj] = s;
  __syncthreads();
  if (tid < 64)
    Mmat[j0 + tid] = smem[tid] + smem[64 + tid] + smem[128 + tid] + smem[192 + tid];
}

// scan: offs = exclusive scan of gcnt (=deg-1); dis = rsqrt(deg). 256 thr.
static __device__ void ph_scan(int tid, int* wsum,
    const int* __restrict__ gcnt, int* __restrict__ offs, float* __restrict__ dis) {
  int lane = tid & 63, wave = tid >> 6;
  const int4* g4 = (const int4*)gcnt;
  int s = 0;
  #pragma unroll
  for (int i = 0; i < 8; ++i) { int4 v = g4[tid * 8 + i]; s += v.x + v.y + v.z + v.w; }
  int sc = s;
  #pragma unroll
  for (int off = 1; off < 64; off <<= 1) {
    int v = __shfl_up(sc, off);
    if (lane >= off) sc += v;
  }
  if (lane == 63) wsum[wave] = sc;
  __syncthreads();
  if (wave == 0 && lane < 4) {
    int v = wsum[lane];
    #pragma unroll
    for (int off = 1; off < 4; off <<= 1) {
      int u = __shfl_up(v, off);
      if (lane >= off) v += u;
    }
    wsum[lane] = v;
  }
  __syncthreads();
  int run = (wave ? wsum[wave - 1] : 0) + sc - s;
  #pragma unroll
  for (int i = 0; i < 8; ++i) {
    int4 v = g4[tid * 8 + i];
    int4 o;
    o.x = run; run += v.x;
    o.y = run; run += v.y;
    o.z = run; run += v.z;
    o.w = run; run += v.w;
    *(int4*)&offs[tid * 32 + i * 4] = o;
    float4 d;
    d.x = rsqrtf((float)(v.x + 1)); d.y = rsqrtf((float)(v.y + 1));
    d.z = rsqrtf((float)(v.z + 1)); d.w = rsqrtf((float)(v.w + 1));
    *(float4*)&dis[tid * 32 + i * 4] = d;
  }
}

// GEMM unit u: xws(bf16) = (X@W)*dis ; att = sigmoid(rinv*(X@M))
static __device__ void ph_gemm(int u, int tid, float* smem,
    const float* __restrict__ x, const float* __restrict__ W,
    const float* __restrict__ Mmat, const float* __restrict__ rinv,
    const float* __restrict__ dis, unsigned short* __restrict__ xws,
    float* __restrict__ att) {
  float* xs  = smem;                 // 4096 f
  float* Wl  = smem + 4096;          // 2048 f
  float* Ml  = smem + 6144;          // 2048 f
  float* rvs = smem + 8192;          // 32 f
  float* dss = smem + 8224;          // 32 f
  int row0 = u * RWB;
  const float4* xsrc = (const float4*)(x + (size_t)row0 * DIM);
  float4* xdst = (float4*)xs;
  #pragma unroll
  for (int i = 0; i < 4; ++i) xdst[tid + 256 * i] = xsrc[tid + 256 * i];
  if (tid < RWB) { rvs[tid] = rinv[row0 + tid]; dss[tid] = dis[row0 + tid]; }

  int ty = tid >> 5, tx = tid & 31;
  int r0 = ty * 4;
  float4 aw[4], am[4];
  #pragma unroll
  for (int j = 0; j < 4; ++j) { aw[j] = make_float4(0,0,0,0); am[j] = make_float4(0,0,0,0); }

  for (int kk = 0; kk < DIM; kk += BK) {
    __syncthreads();
    const float4* Ws = (const float4*)(W + (size_t)kk * DIM);
    const float4* Ms = (const float4*)(Mmat + (size_t)kk * DIM);
    float4 w0s = Ws[tid], w1s = Ws[tid + 256];
    float4 m0s = Ms[tid], m1s = Ms[tid + 256];
    ((float4*)Wl)[tid]       = w0s;
    ((float4*)Wl)[tid + 256] = w1s;
    ((float4*)Ml)[tid]       = m0s;
    ((float4*)Ml)[tid + 256] = m1s;
    __syncthreads();
    #pragma unroll
    for (int k4 = 0; k4 < BK; k4 += 4) {
      float4 xf[4];
      #pragma unroll
      for (int j = 0; j < 4; ++j)
        xf[j] = *(const float4*)&xs[(r0 + j) * DIM + kk + k4];
      #pragma unroll
      for (int k = 0; k < 4; ++k) {
        float4 wv = *(const float4*)&Wl[(k4 + k) * DIM + tx * 4];
        float4 mv = *(const float4*)&Ml[(k4 + k) * DIM + tx * 4];
        #pragma unroll
        for (int j = 0; j < 4; ++j) {
          float xv = ((const float*)&xf[j])[k];
          aw[j].x += xv * wv.x; aw[j].y += xv * wv.y;
          aw[j].z += xv * wv.z; aw[j].w += xv * wv.w;
          am[j].x += xv * mv.x; am[j].y += xv * mv.y;
          am[j].z += xv * mv.z; am[j].w += xv * mv.w;
        }
      }
    }
  }
  #pragma unroll
  for (int j = 0; j < 4; ++j) {
    int row = row0 + r0 + j;
    float rv = rvs[r0 + j], ds = dss[r0 + j];
    size_t o = (size_t)row * DIM + tx * 4;
    ushort4 wb;
    wb.x = f2bf(aw[j].x * ds);
    wb.y = f2bf(aw[j].y * ds);
    wb.z = f2bf(aw[j].z * ds);
    wb.w = f2bf(aw[j].w * ds);
    *(ushort4*)&xws[o] = wb;
    float4 g;
    g.x = 1.0f / (1.0f + __expf(-am[j].x * rv));
    g.y = 1.0f / (1.0f + __expf(-am[j].y * rv));
    g.z = 1.0f / (1.0f + __expf(-am[j].z * rv));
    g.w = 1.0f / (1.0f + __expf(-am[j].w * rv));
    *(float4*)&att[o] = g;
  }
}

// placement chunk u: pos = offs[tgt] + slot  (no atomics)
static __device__ void ph_place(int u, int tid,
    const int* __restrict__ ei, const int* __restrict__ offs,
    const int* __restrict__ slot, int* __restrict__ sorted) {
  int e0 = u * EPB + tid * 4;
  int4 sv = *(const int4*)(ei + e0);          // sources
  int4 cv = *(const int4*)(ei + NE + e0);     // targets
  int4 sl = *(const int4*)(slot + e0);
  sorted[offs[cv.x] + sl.x] = sv.x;
  sorted[offs[cv.y] + sl.y] = sv.y;
  sorted[offs[cv.z] + sl.z] = sv.z;
  sorted[offs[cv.w] + sl.w] = sv.w;
}

// gather unit u: 2 nodes (128 threads each)
static __device__ void ph_gather(int u, int tid,
    const int* __restrict__ offs, const int* __restrict__ gcnt,
    const float* __restrict__ dis, const unsigned short* __restrict__ xws,
    const float* __restrict__ att, const float* __restrict__ bias,
    const int* __restrict__ sorted, float* __restrict__ out) {
  int sub = tid >> 7, t = tid & 127;
  int c = u * 2 + sub;
  int base = offs[c];
  int cnt  = gcnt[c];                          // deg-1
  float acc = bf2f(xws[(size_t)c * DIM + t]);  // self-loop term
  int k = 0;
  for (; k + 4 <= cnt; k += 4) {
    int s0 = sorted[base + k + 0];
    int s1 = sorted[base + k + 1];
    int s2 = sorted[base + k + 2];
    int s3 = sorted[base + k + 3];
    float v0 = bf2f(xws[(size_t)s0 * DIM + t]);
    float v1 = bf2f(xws[(size_t)s1 * DIM + t]);
    float v2 = bf2f(xws[(size_t)s2 * DIM + t]);
    float v3 = bf2f(xws[(size_t)s3 * DIM + t]);
    acc += v0 + v1 + v2 + v3;
  }
  for (; k < cnt; ++k)
    acc += bf2f(xws[(size_t)sorted[base + k] * DIM + t]);
  float g = acc * dis[c] + bias[t];
  out[(size_t)c * DIM + t] = g * att[(size_t)c * DIM + t];
}

// ==================== cooperative single-launch kernel ====================
__global__ __launch_bounds__(256, 2) void k_all(
    const float* __restrict__ x, const int* __restrict__ ei,
    const float* __restrict__ W, const float* __restrict__ bias,
    float* __restrict__ out,
    unsigned short* __restrict__ xws, float* __restrict__ att,
    float* __restrict__ Mpart, float* __restrict__ Mmat,
    float* __restrict__ rinv, float* __restrict__ dis,
    int* __restrict__ gcnt, int* __restrict__ offs,
    int* __restrict__ slot, int* __restrict__ sorted) {
  cg::grid_group grid = cg::this_grid();
  __shared__ float smem[SMEMF];
  int bid = blockIdx.x, tid = threadIdx.x, G = gridDim.x;

  for (int u = bid; u < XB + HB; u += G) {       // A: xtx | hist
    if (u < XB) ph_xtx(u, tid, smem, x, rinv, Mpart);
    else        ph_hist(u - XB, tid, (int*)smem, ei, gcnt, slot);
    __syncthreads();
  }
  grid.sync();
  for (int u = bid; u < 257; u += G) {           // B: M reduce | scan
    if (u < 256) ph_mred(u, tid, smem, Mpart, Mmat);
    else         ph_scan(tid, (int*)smem, gcnt, offs, dis);
    __syncthreads();
  }
  grid.sync();
  for (int u = bid; u < NN / RWB + HB; u += G) { // C: GEMM | placement
    if (u < NN / RWB) ph_gemm(u, tid, smem, x, W, Mmat, rinv, dis, xws, att);
    else              ph_place(u - NN / RWB, tid, ei, offs, slot, sorted);
    __syncthreads();
  }
  grid.sync();
  for (int u = bid; u < NN / 2; u += G)          // D: gather
    ph_gather(u, tid, offs, gcnt, dis, xws, att, bias, sorted, out);
}

// ==================== non-coop fallback kernels (same units) ====================
__global__ __launch_bounds__(256, 2) void k_pA(const float* __restrict__ x,
    const int* __restrict__ ei, float* __restrict__ rinv,
    float* __restrict__ Mpart, int* __restrict__ gcnt, int* __restrict__ slot) {
  __shared__ float smem[SMEMF];
  int u = blockIdx.x, tid = threadIdx.x;
  if (u < XB) ph_xtx(u, tid, smem, x, rinv, Mpart);
  else        ph_hist(u - XB, tid, (int*)smem, ei, gcnt, slot);
}
__global__ __launch_bounds__(256, 2) void k_pB(const float* __restrict__ Mpart,
    float* __restrict__ Mmat, const int* __restrict__ gcnt,
    int* __restrict__ offs, float* __restrict__ dis) {
  __shared__ float smem[SMEMF];
  int u = blockIdx.x, tid = threadIdx.x;
  if (u < 256) ph_mred(u, tid, smem, Mpart, Mmat);
  else         ph_scan(tid, (int*)smem, gcnt, offs, dis);
}
__global__ __launch_bounds__(256, 2) void k_pC(const float* __restrict__ x,
    const float* __restrict__ W, const float* __restrict__ Mmat,
    const float* __restrict__ rinv, const float* __restrict__ dis,
    const int* __restrict__ ei, const int* __restrict__ offs,
    const int* __restrict__ slot, int* __restrict__ sorted,
    unsigned short* __restrict__ xws, float* __restrict__ att) {
  __shared__ float smem[SMEMF];
  int u = blockIdx.x, tid = threadIdx.x;
  if (u < NN / RWB) ph_gemm(u, tid, smem, x, W, Mmat, rinv, dis, xws, att);
  else              ph_place(u - NN / RWB, tid, ei, offs, slot, sorted);
}
__global__ __launch_bounds__(256, 2) void k_pD(const int* __restrict__ offs,
    const int* __restrict__ gcnt, const float* __restrict__ dis,
    const unsigned short* __restrict__ xws, const float* __restrict__ att,
    const float* __restrict__ bias, const int* __restrict__ sorted,
    float* __restrict__ out) {
  ph_gather(blockIdx.x, threadIdx.x, offs, gcnt, dis, xws, att, bias, sorted, out);
}

// ---------------------------------------------------------------------- launch
extern "C" void kernel_launch(void* const* d_in, const int* in_sizes, int n_in,
                              void* d_out, int out_size, void* d_ws, size_t ws_size,
                              hipStream_t stream) {
  const float* x  = (const float*)d_in[0];
  const int*   ei = (const int*)  d_in[1];
  const float* W  = (const float*)d_in[2];
  const float* b  = (const float*)d_in[3];
  float* out = (float*)d_out;

  // ws layout (~15.5 MB)
  unsigned short* xws = (unsigned short*)d_ws;        // NN*DIM bf16
  float* att   = (float*)(xws + (size_t)NN * DIM);    // NN*DIM
  float* Mpart = att + (size_t)NN * DIM;              // XB*DIM*DIM
  float* Mmat  = Mpart + (size_t)XB * DIM * DIM;      // DIM*DIM
  float* rinv  = Mmat + DIM * DIM;                    // NN
  float* dis   = rinv + NN;                           // NN
  int*   gcnt  = (int*)(dis + NN);                    // NN (zeroed below)
  int*   offs  = gcnt + NN;                           // NN
  int*   slot  = offs + NN;                           // NE
  int*   sorted= slot + NE;                           // NE

  hipMemsetAsync(gcnt, 0, NN * sizeof(int), stream);

  void* args[] = {(void*)&x, (void*)&ei, (void*)&W, (void*)&b, (void*)&out,
                  (void*)&xws, (void*)&att, (void*)&Mpart, (void*)&Mmat,
                  (void*)&rinv, (void*)&dis, (void*)&gcnt, (void*)&offs,
                  (void*)&slot, (void*)&sorted};
  hipError_t e = hipLaunchCooperativeKernel((const void*)k_all, dim3(512),
                                            dim3(256), args, 0, stream);
  if (e != hipSuccess)
    e = hipLaunchCooperativeKernel((const void*)k_all, dim3(256),
                                   dim3(256), args, 0, stream);
  if (e != hipSuccess) {
    (void)hipGetLastError();   // clear sticky error from failed coop attempts
    k_pA<<<XB + HB, 256, 0, stream>>>(x, ei, rinv, Mpart, gcnt, slot);
    k_pB<<<257, 256, 0, stream>>>(Mpart, Mmat, gcnt, offs, dis);
    k_pC<<<NN / RWB + HB, 256, 0, stream>>>(x, W, Mmat, rinv, dis, ei, offs,
                                            slot, sorted, xws, att);
    k_pD<<<NN / 2, 256, 0, stream>>>(offs, gcnt, dis, xws, att, b, sorted, out);
  }
}

// Round 10
// 117.489 us; speedup vs baseline: 2.7349x; 2.7349x over previous
//
#include <hip/hip_runtime.h>
#include <math.h>

#define NN   8192
#define DIM  128
#define NE   262144
#define XB   128          // xtx units (64 rows each)
#define HB   64           // histogram chunks
#define EPB  (NE / HB)    // 4096 edges per chunk
#define RWB  32           // rows per GEMM unit (4 per thread)
#define BK   16           // k-chunk rows of W/M staged in LDS
#define SMEMF (64 * DIM + 64)   // 8256 floats = 33 KB

// bf16 via explicit bit math (this ROCm's __hip_bfloat16 lacks .data)
static __device__ __forceinline__ unsigned short f2bf(float f) {
  unsigned int u = __float_as_uint(f);
  return (unsigned short)((u + 0x7FFFu + ((u >> 16) & 1u)) >> 16);   // RNE
}
static __device__ __forceinline__ float bf2f(unsigned short h) {
  return __uint_as_float((unsigned int)h << 16);
}

// ==================== phase unit functions (block-scoped) ====================

// xtx unit u: stage 64 rows, write rinv for them, emit Mpart[u]
static __device__ void ph_xtx(int u, int tid, float* smem,
    const float* __restrict__ x, float* __restrict__ rinv,
    float* __restrict__ Mpart) {
  float* xs  = smem;
  float* rvs = smem + 64 * DIM;
  int row0 = u * 64;
  const float4* xsrc = (const float4*)(x + (size_t)row0 * DIM);
  float4* xdst = (float4*)xs;
  #pragma unroll
  for (int i = 0; i < 8; ++i) xdst[tid + 256 * i] = xsrc[tid + 256 * i];
  __syncthreads();
  int rr = tid >> 2, q = tid & 3;
  const float4* xr = (const float4*)&xs[rr * DIM + q * 32];
  float ss = 0.f;
  #pragma unroll
  for (int i = 0; i < 8; ++i) {
    float4 v = xr[i];
    ss += v.x * v.x + v.y * v.y + v.z * v.z + v.w * v.w;
  }
  ss += __shfl_xor(ss, 1);
  ss += __shfl_xor(ss, 2);
  if (q == 0) { float rv = 1.0f / sqrtf(ss); rvs[rr] = rv; rinv[row0 + rr] = rv; }
  __syncthreads();

  int ty = tid >> 4, tx = tid & 15;
  float acc[8][8];
  #pragma unroll
  for (int i = 0; i < 8; ++i)
    #pragma unroll
    for (int j = 0; j < 8; ++j) acc[i][j] = 0.f;
  #pragma unroll 2
  for (int r = 0; r < 64; ++r) {
    float4 a0 = *(const float4*)&xs[r * DIM + ty * 8];
    float4 a1 = *(const float4*)&xs[r * DIM + ty * 8 + 4];
    float4 b0 = *(const float4*)&xs[r * DIM + tx * 8];
    float4 b1 = *(const float4*)&xs[r * DIM + tx * 8 + 4];
    float rv = rvs[r];
    float a[8] = {a0.x * rv, a0.y * rv, a0.z * rv, a0.w * rv,
                  a1.x * rv, a1.y * rv, a1.z * rv, a1.w * rv};
    float b[8] = {b0.x, b0.y, b0.z, b0.w, b1.x, b1.y, b1.z, b1.w};
    #pragma unroll
    for (int i = 0; i < 8; ++i)
      #pragma unroll
      for (int j = 0; j < 8; ++j) acc[i][j] += a[i] * b[j];
  }
  float* o = Mpart + (size_t)u * (DIM * DIM);
  #pragma unroll
  for (int i = 0; i < 8; ++i) {
    *(float4*)&o[(ty * 8 + i) * DIM + tx * 8]     = make_float4(acc[i][0], acc[i][1], acc[i][2], acc[i][3]);
    *(float4*)&o[(ty * 8 + i) * DIM + tx * 8 + 4] = make_float4(acc[i][4], acc[i][5], acc[i][6], acc[i][7]);
  }
}

// hist chunk h: LDS histogram; 1 global atomic per TOUCHED bin claims the
// chunk's global base; per-edge final slot = base + local rank. No partial
// matrix, no rank array, no second pass.
static __device__ void ph_hist(int h, int tid, int* ldeg,
    const int* __restrict__ ei, int* __restrict__ gcnt, int* __restrict__ slot) {
  int4* lz = (int4*)ldeg;
  #pragma unroll
  for (int i = tid; i < NN / 4; i += 256) lz[i] = make_int4(0, 0, 0, 0);
  __syncthreads();
  int e0 = h * EPB + tid * 16;
  int4 c0 = *(const int4*)(ei + NE + e0);       // targets
  int4 c1 = *(const int4*)(ei + NE + e0 + 4);
  int4 c2 = *(const int4*)(ei + NE + e0 + 8);
  int4 c3 = *(const int4*)(ei + NE + e0 + 12);
  int r0  = atomicAdd(&ldeg[c0.x], 1);
  int r1  = atomicAdd(&ldeg[c0.y], 1);
  int r2  = atomicAdd(&ldeg[c0.z], 1);
  int r3  = atomicAdd(&ldeg[c0.w], 1);
  int r4  = atomicAdd(&ldeg[c1.x], 1);
  int r5  = atomicAdd(&ldeg[c1.y], 1);
  int r6  = atomicAdd(&ldeg[c1.z], 1);
  int r7  = atomicAdd(&ldeg[c1.w], 1);
  int r8  = atomicAdd(&ldeg[c2.x], 1);
  int r9  = atomicAdd(&ldeg[c2.y], 1);
  int r10 = atomicAdd(&ldeg[c2.z], 1);
  int r11 = atomicAdd(&ldeg[c2.w], 1);
  int r12 = atomicAdd(&ldeg[c3.x], 1);
  int r13 = atomicAdd(&ldeg[c3.y], 1);
  int r14 = atomicAdd(&ldeg[c3.z], 1);
  int r15 = atomicAdd(&ldeg[c3.w], 1);
  __syncthreads();
  int binb = tid * 32;
  #pragma unroll
  for (int i = 0; i < 8; ++i) {
    int4 v = *(int4*)&ldeg[binb + i * 4];
    if (v.x) ldeg[binb + i * 4 + 0] = atomicAdd(&gcnt[binb + i * 4 + 0], v.x);
    if (v.y) ldeg[binb + i * 4 + 1] = atomicAdd(&gcnt[binb + i * 4 + 1], v.y);
    if (v.z) ldeg[binb + i * 4 + 2] = atomicAdd(&gcnt[binb + i * 4 + 2], v.z);
    if (v.w) ldeg[binb + i * 4 + 3] = atomicAdd(&gcnt[binb + i * 4 + 3], v.w);
  }
  __syncthreads();
  int4 s0 = make_int4(ldeg[c0.x] + r0,  ldeg[c0.y] + r1,  ldeg[c0.z] + r2,  ldeg[c0.w] + r3);
  int4 s1 = make_int4(ldeg[c1.x] + r4,  ldeg[c1.y] + r5,  ldeg[c1.z] + r6,  ldeg[c1.w] + r7);
  int4 s2 = make_int4(ldeg[c2.x] + r8,  ldeg[c2.y] + r9,  ldeg[c2.z] + r10, ldeg[c2.w] + r11);
  int4 s3 = make_int4(ldeg[c3.x] + r12, ldeg[c3.y] + r13, ldeg[c3.z] + r14, ldeg[c3.w] + r15);
  *(int4*)(slot + e0)      = s0;
  *(int4*)(slot + e0 + 4)  = s1;
  *(int4*)(slot + e0 + 8)  = s2;
  *(int4*)(slot + e0 + 12) = s3;
}

// M-reduce unit u: sum 128 partials for 64 entries, 4-way split-K via LDS
static __device__ void ph_mred(int u, int tid, float* smem,
    const float* __restrict__ Mpart, float* __restrict__ Mmat) {
  int j0 = u * 64;
  int jj = tid & 63, sub = tid >> 6;
  const float* mp = Mpart + (size_t)(sub * 32) * (DIM * DIM) + j0;
  float s = 0.f;
  #pragma unroll 4
  for (int k = 0; k < 32; ++k) s += mp[(size_t)k * (DIM * DIM) + jj];
  smem[sub * 64 + jj] = s;
  __syncthreads();
  if (tid < 64)
    Mmat[j0 + tid] = smem[tid] + smem[64 + tid] + smem[128 + tid] + smem[192 + tid];
}

// scan: offs = exclusive scan of gcnt (=deg-1); dis = rsqrt(deg). 256 thr.
static __device__ void ph_scan(int tid, int* wsum,
    const int* __restrict__ gcnt, int* __restrict__ offs, float* __restrict__ dis) {
  int lane = tid & 63, wave = tid >> 6;
  const int4* g4 = (const int4*)gcnt;
  int s = 0;
  #pragma unroll
  for (int i = 0; i < 8; ++i) { int4 v = g4[tid * 8 + i]; s += v.x + v.y + v.z + v.w; }
  int sc = s;
  #pragma unroll
  for (int off = 1; off < 64; off <<= 1) {
    int v = __shfl_up(sc, off);
    if (lane >= off) sc += v;
  }
  if (lane == 63) wsum[wave] = sc;
  __syncthreads();
  if (wave == 0 && lane < 4) {
    int v = wsum[lane];
    #pragma unroll
    for (int off = 1; off < 4; off <<= 1) {
      int u = __shfl_up(v, off);
      if (lane >= off) v += u;
    }
    wsum[lane] = v;
  }
  __syncthreads();
  int run = (wave ? wsum[wave - 1] : 0) + sc - s;
  #pragma unroll
  for (int i = 0; i < 8; ++i) {
    int4 v = g4[tid * 8 + i];
    int4 o;
    o.x = run; run += v.x;
    o.y = run; run += v.y;
    o.z = run; run += v.z;
    o.w = run; run += v.w;
    *(int4*)&offs[tid * 32 + i * 4] = o;
    float4 d;
    d.x = rsqrtf((float)(v.x + 1)); d.y = rsqrtf((float)(v.y + 1));
    d.z = rsqrtf((float)(v.z + 1)); d.w = rsqrtf((float)(v.w + 1));
    *(float4*)&dis[tid * 32 + i * 4] = d;
  }
}

// GEMM unit u: xws(bf16) = (X@W)*dis ; att = sigmoid(rinv*(X@M))
static __device__ void ph_gemm(int u, int tid, float* smem,
    const float* __restrict__ x, const float* __restrict__ W,
    const float* __restrict__ Mmat, const float* __restrict__ rinv,
    const float* __restrict__ dis, unsigned short* __restrict__ xws,
    float* __restrict__ att) {
  float* xs  = smem;                 // 4096 f
  float* Wl  = smem + 4096;          // 2048 f
  float* Ml  = smem + 6144;          // 2048 f
  float* rvs = smem + 8192;          // 32 f
  float* dss = smem + 8224;          // 32 f
  int row0 = u * RWB;
  const float4* xsrc = (const float4*)(x + (size_t)row0 * DIM);
  float4* xdst = (float4*)xs;
  #pragma unroll
  for (int i = 0; i < 4; ++i) xdst[tid + 256 * i] = xsrc[tid + 256 * i];
  if (tid < RWB) { rvs[tid] = rinv[row0 + tid]; dss[tid] = dis[row0 + tid]; }

  int ty = tid >> 5, tx = tid & 31;
  int r0 = ty * 4;
  float4 aw[4], am[4];
  #pragma unroll
  for (int j = 0; j < 4; ++j) { aw[j] = make_float4(0,0,0,0); am[j] = make_float4(0,0,0,0); }

  for (int kk = 0; kk < DIM; kk += BK) {
    __syncthreads();
    const float4* Ws = (const float4*)(W + (size_t)kk * DIM);
    const float4* Ms = (const float4*)(Mmat + (size_t)kk * DIM);
    float4 w0s = Ws[tid], w1s = Ws[tid + 256];
    float4 m0s = Ms[tid], m1s = Ms[tid + 256];
    ((float4*)Wl)[tid]       = w0s;
    ((float4*)Wl)[tid + 256] = w1s;
    ((float4*)Ml)[tid]       = m0s;
    ((float4*)Ml)[tid + 256] = m1s;
    __syncthreads();
    #pragma unroll
    for (int k4 = 0; k4 < BK; k4 += 4) {
      float4 xf[4];
      #pragma unroll
      for (int j = 0; j < 4; ++j)
        xf[j] = *(const float4*)&xs[(r0 + j) * DIM + kk + k4];
      #pragma unroll
      for (int k = 0; k < 4; ++k) {
        float4 wv = *(const float4*)&Wl[(k4 + k) * DIM + tx * 4];
        float4 mv = *(const float4*)&Ml[(k4 + k) * DIM + tx * 4];
        #pragma unroll
        for (int j = 0; j < 4; ++j) {
          float xv = ((const float*)&xf[j])[k];
          aw[j].x += xv * wv.x; aw[j].y += xv * wv.y;
          aw[j].z += xv * wv.z; aw[j].w += xv * wv.w;
          am[j].x += xv * mv.x; am[j].y += xv * mv.y;
          am[j].z += xv * mv.z; am[j].w += xv * mv.w;
        }
      }
    }
  }
  #pragma unroll
  for (int j = 0; j < 4; ++j) {
    int row = row0 + r0 + j;
    float rv = rvs[r0 + j], ds = dss[r0 + j];
    size_t o = (size_t)row * DIM + tx * 4;
    ushort4 wb;
    wb.x = f2bf(aw[j].x * ds);
    wb.y = f2bf(aw[j].y * ds);
    wb.z = f2bf(aw[j].z * ds);
    wb.w = f2bf(aw[j].w * ds);
    *(ushort4*)&xws[o] = wb;
    float4 g;
    g.x = 1.0f / (1.0f + __expf(-am[j].x * rv));
    g.y = 1.0f / (1.0f + __expf(-am[j].y * rv));
    g.z = 1.0f / (1.0f + __expf(-am[j].z * rv));
    g.w = 1.0f / (1.0f + __expf(-am[j].w * rv));
    *(float4*)&att[o] = g;
  }
}

// placement chunk u: pos = offs[tgt] + slot  (no atomics)
static __device__ void ph_place(int u, int tid,
    const int* __restrict__ ei, const int* __restrict__ offs,
    const int* __restrict__ slot, int* __restrict__ sorted) {
  int e0 = u * EPB + tid * 16;
  #pragma unroll
  for (int i = 0; i < 4; ++i) {
    int4 sv = *(const int4*)(ei + e0 + i * 4);          // sources
    int4 cv = *(const int4*)(ei + NE + e0 + i * 4);     // targets
    int4 sl = *(const int4*)(slot + e0 + i * 4);
    sorted[offs[cv.x] + sl.x] = sv.x;
    sorted[offs[cv.y] + sl.y] = sv.y;
    sorted[offs[cv.z] + sl.z] = sv.z;
    sorted[offs[cv.w] + sl.w] = sv.w;
  }
}

// ==================== kernels (fat grids — TLP is king for tail phases) ====
__global__ __launch_bounds__(256) void k_pA(const float* __restrict__ x,
    const int* __restrict__ ei, float* __restrict__ rinv,
    float* __restrict__ Mpart, int* __restrict__ gcnt, int* __restrict__ slot) {
  __shared__ float smem[SMEMF];
  int u = blockIdx.x, tid = threadIdx.x;
  if (u < XB) ph_xtx(u, tid, smem, x, rinv, Mpart);
  else        ph_hist(u - XB, tid, (int*)smem, ei, gcnt, slot);
}
__global__ __launch_bounds__(256) void k_pB(const float* __restrict__ Mpart,
    float* __restrict__ Mmat, const int* __restrict__ gcnt,
    int* __restrict__ offs, float* __restrict__ dis) {
  __shared__ float smem[SMEMF];
  int u = blockIdx.x, tid = threadIdx.x;
  if (u < 256) ph_mred(u, tid, smem, Mpart, Mmat);
  else         ph_scan(tid, (int*)smem, gcnt, offs, dis);
}
__global__ __launch_bounds__(256) void k_pC(const float* __restrict__ x,
    const float* __restrict__ W, const float* __restrict__ Mmat,
    const float* __restrict__ rinv, const float* __restrict__ dis,
    const int* __restrict__ ei, const int* __restrict__ offs,
    const int* __restrict__ slot, int* __restrict__ sorted,
    unsigned short* __restrict__ xws, float* __restrict__ att) {
  __shared__ float smem[SMEMF];
  int u = blockIdx.x, tid = threadIdx.x;
  if (u < NN / RWB) ph_gemm(u, tid, smem, x, W, Mmat, rinv, dis, xws, att);
  else              ph_place(u - NN / RWB, tid, ei, offs, slot, sorted);
}
// gather: one node per 128-thread block (8192 blocks — max TLP, r9 lesson)
__global__ __launch_bounds__(128) void k_pD(const int* __restrict__ offs,
    const int* __restrict__ gcnt, const float* __restrict__ dis,
    const unsigned short* __restrict__ xws, const float* __restrict__ att,
    const float* __restrict__ bias, const int* __restrict__ sorted,
    float* __restrict__ out) {
  int c = blockIdx.x, t = threadIdx.x;
  int base = offs[c];
  int cnt  = gcnt[c];                          // deg-1
  float acc = bf2f(xws[(size_t)c * DIM + t]);  // self-loop term
  int k = 0;
  for (; k + 4 <= cnt; k += 4) {
    int s0 = sorted[base + k + 0];
    int s1 = sorted[base + k + 1];
    int s2 = sorted[base + k + 2];
    int s3 = sorted[base + k + 3];
    float v0 = bf2f(xws[(size_t)s0 * DIM + t]);
    float v1 = bf2f(xws[(size_t)s1 * DIM + t]);
    float v2 = bf2f(xws[(size_t)s2 * DIM + t]);
    float v3 = bf2f(xws[(size_t)s3 * DIM + t]);
    acc += v0 + v1 + v2 + v3;
  }
  for (; k < cnt; ++k)
    acc += bf2f(xws[(size_t)sorted[base + k] * DIM + t]);
  float g = acc * dis[c] + bias[t];
  out[(size_t)c * DIM + t] = g * att[(size_t)c * DIM + t];
}

// ---------------------------------------------------------------------- launch
extern "C" void kernel_launch(void* const* d_in, const int* in_sizes, int n_in,
                              void* d_out, int out_size, void* d_ws, size_t ws_size,
                              hipStream_t stream) {
  const float* x  = (const float*)d_in[0];
  const int*   ei = (const int*)  d_in[1];
  const float* W  = (const float*)d_in[2];
  const float* b  = (const float*)d_in[3];
  float* out = (float*)d_out;

  // ws layout (~15.5 MB)
  unsigned short* xws = (unsigned short*)d_ws;        // NN*DIM bf16
  float* att   = (float*)(xws + (size_t)NN * DIM);    // NN*DIM
  float* Mpart = att + (size_t)NN * DIM;              // XB*DIM*DIM
  float* Mmat  = Mpart + (size_t)XB * DIM * DIM;      // DIM*DIM
  float* rinv  = Mmat + DIM * DIM;                    // NN
  float* dis   = rinv + NN;                           // NN
  int*   gcnt  = (int*)(dis + NN);                    // NN (zeroed below)
  int*   offs  = gcnt + NN;                           // NN
  int*   slot  = offs + NN;                           // NE
  int*   sorted= slot + NE;                           // NE

  hipMemsetAsync(gcnt, 0, NN * sizeof(int), stream);

  k_pA<<<XB + HB, 256, 0, stream>>>(x, ei, rinv, Mpart, gcnt, slot);
  k_pB<<<257, 256, 0, stream>>>(Mpart, Mmat, gcnt, offs, dis);
  k_pC<<<NN / RWB + HB, 256, 0, stream>>>(x, W, Mmat, rinv, dis, ei, offs,
                                          slot, sorted, xws, att);
  k_pD<<<NN, 128, 0, stream>>>(offs, gcnt, dis, xws, att, b, sorted, out);
}

// Round 11
// 116.378 us; speedup vs baseline: 2.7610x; 1.0095x over previous
//
#include <hip/hip_runtime.h>
#include <math.h>

#define NN   8192
#define DIM  128
#define NE   262144
#define XB   128          // xtx units (64 rows each)
#define HBH  64           // histogram chunks (256-thr, 4096 edges)
#define HEB  (NE / HBH)
#define PBP  128          // placement chunks (128-thr, 2048 edges)
#define PEB  (NE / PBP)
#define RWB  32           // rows per GEMM unit
#define BK   16           // k-chunk rows of W/M staged in LDS
#define XSS  132          // padded xs row stride in kC (breaks row-stride conflicts)
#define SMEMF 8448

// bf16 via explicit bit math (this ROCm's __hip_bfloat16 lacks .data)
static __device__ __forceinline__ unsigned short f2bf(float f) {
  unsigned int u = __float_as_uint(f);
  return (unsigned short)((u + 0x7FFFu + ((u >> 16) & 1u)) >> 16);   // RNE
}
static __device__ __forceinline__ float bf2f(unsigned int h) {
  return __uint_as_float(h << 16);
}

// ==================== phase unit functions ====================

// xtx unit u (256 thr): stage 64 rows, write rinv, emit Mpart[u].
// Fragments split 4+4 (tx*4 / 64+tx*4): 2-way LDS conflicts = free
// (old tx*8 layout was 4-way — r9 measured 830k conflict cycles).
static __device__ void ph_xtx(int u, int tid, float* smem,
    const float* __restrict__ x, float* __restrict__ rinv,
    float* __restrict__ Mpart) {
  float* xs  = smem;
  float* rvs = smem + 64 * DIM;
  int row0 = u * 64;
  const float4* xsrc = (const float4*)(x + (size_t)row0 * DIM);
  float4* xdst = (float4*)xs;
  #pragma unroll
  for (int i = 0; i < 8; ++i) xdst[tid + 256 * i] = xsrc[tid + 256 * i];
  __syncthreads();
  int rr = tid >> 2, q = tid & 3;
  const float4* xr = (const float4*)&xs[rr * DIM + q * 32];
  float ss = 0.f;
  #pragma unroll
  for (int i = 0; i < 8; ++i) {
    float4 v = xr[i];
    ss += v.x * v.x + v.y * v.y + v.z * v.z + v.w * v.w;
  }
  ss += __shfl_xor(ss, 1);
  ss += __shfl_xor(ss, 2);
  if (q == 0) { float rv = 1.0f / sqrtf(ss); rvs[rr] = rv; rinv[row0 + rr] = rv; }
  __syncthreads();

  int ty = tid >> 4, tx = tid & 15;
  float acc[8][8];
  #pragma unroll
  for (int i = 0; i < 8; ++i)
    #pragma unroll
    for (int j = 0; j < 8; ++j) acc[i][j] = 0.f;
  #pragma unroll 2
  for (int r = 0; r < 64; ++r) {
    float4 a0 = *(const float4*)&xs[r * DIM + ty * 4];
    float4 a1 = *(const float4*)&xs[r * DIM + 64 + ty * 4];
    float4 b0 = *(const float4*)&xs[r * DIM + tx * 4];
    float4 b1 = *(const float4*)&xs[r * DIM + 64 + tx * 4];
    float rv = rvs[r];
    float a[8] = {a0.x * rv, a0.y * rv, a0.z * rv, a0.w * rv,
                  a1.x * rv, a1.y * rv, a1.z * rv, a1.w * rv};
    float b[8] = {b0.x, b0.y, b0.z, b0.w, b1.x, b1.y, b1.z, b1.w};
    #pragma unroll
    for (int i = 0; i < 8; ++i)
      #pragma unroll
      for (int j = 0; j < 8; ++j) acc[i][j] += a[i] * b[j];
  }
  float* o = Mpart + (size_t)u * (DIM * DIM);
  #pragma unroll
  for (int i = 0; i < 8; ++i) {
    int row = (i < 4) ? (ty * 4 + i) : (64 + ty * 4 + (i - 4));
    *(float4*)&o[row * DIM + tx * 4]      = make_float4(acc[i][0], acc[i][1], acc[i][2], acc[i][3]);
    *(float4*)&o[row * DIM + 64 + tx * 4] = make_float4(acc[i][4], acc[i][5], acc[i][6], acc[i][7]);
  }
}

// hist chunk h (256 thr): LDS histogram; 1 global atomic per TOUCHED bin
// claims the chunk's base; per-edge final slot = base + local rank.
static __device__ void ph_hist(int h, int tid, int* ldeg,
    const int* __restrict__ ei, int* __restrict__ gcnt, int* __restrict__ slot) {
  int4* lz = (int4*)ldeg;
  #pragma unroll
  for (int i = tid; i < NN / 4; i += 256) lz[i] = make_int4(0, 0, 0, 0);
  __syncthreads();
  int e0 = h * HEB + tid * 16;
  int4 c0 = *(const int4*)(ei + NE + e0);       // targets
  int4 c1 = *(const int4*)(ei + NE + e0 + 4);
  int4 c2 = *(const int4*)(ei + NE + e0 + 8);
  int4 c3 = *(const int4*)(ei + NE + e0 + 12);
  int r0  = atomicAdd(&ldeg[c0.x], 1);
  int r1  = atomicAdd(&ldeg[c0.y], 1);
  int r2  = atomicAdd(&ldeg[c0.z], 1);
  int r3  = atomicAdd(&ldeg[c0.w], 1);
  int r4  = atomicAdd(&ldeg[c1.x], 1);
  int r5  = atomicAdd(&ldeg[c1.y], 1);
  int r6  = atomicAdd(&ldeg[c1.z], 1);
  int r7  = atomicAdd(&ldeg[c1.w], 1);
  int r8  = atomicAdd(&ldeg[c2.x], 1);
  int r9  = atomicAdd(&ldeg[c2.y], 1);
  int r10 = atomicAdd(&ldeg[c2.z], 1);
  int r11 = atomicAdd(&ldeg[c2.w], 1);
  int r12 = atomicAdd(&ldeg[c3.x], 1);
  int r13 = atomicAdd(&ldeg[c3.y], 1);
  int r14 = atomicAdd(&ldeg[c3.z], 1);
  int r15 = atomicAdd(&ldeg[c3.w], 1);
  __syncthreads();
  int binb = tid * 32;
  #pragma unroll
  for (int i = 0; i < 8; ++i) {
    int4 v = *(int4*)&ldeg[binb + i * 4];
    if (v.x) ldeg[binb + i * 4 + 0] = atomicAdd(&gcnt[binb + i * 4 + 0], v.x);
    if (v.y) ldeg[binb + i * 4 + 1] = atomicAdd(&gcnt[binb + i * 4 + 1], v.y);
    if (v.z) ldeg[binb + i * 4 + 2] = atomicAdd(&gcnt[binb + i * 4 + 2], v.z);
    if (v.w) ldeg[binb + i * 4 + 3] = atomicAdd(&gcnt[binb + i * 4 + 3], v.w);
  }
  __syncthreads();
  int4 s0 = make_int4(ldeg[c0.x] + r0,  ldeg[c0.y] + r1,  ldeg[c0.z] + r2,  ldeg[c0.w] + r3);
  int4 s1 = make_int4(ldeg[c1.x] + r4,  ldeg[c1.y] + r5,  ldeg[c1.z] + r6,  ldeg[c1.w] + r7);
  int4 s2 = make_int4(ldeg[c2.x] + r8,  ldeg[c2.y] + r9,  ldeg[c2.z] + r10, ldeg[c2.w] + r11);
  int4 s3 = make_int4(ldeg[c3.x] + r12, ldeg[c3.y] + r13, ldeg[c3.z] + r14, ldeg[c3.w] + r15);
  *(int4*)(slot + e0)      = s0;
  *(int4*)(slot + e0 + 4)  = s1;
  *(int4*)(slot + e0 + 8)  = s2;
  *(int4*)(slot + e0 + 12) = s3;
}

// M-reduce unit u (256 thr): sum 128 partials for 64 entries, split-K via LDS
static __device__ void ph_mred(int u, int tid, float* smem,
    const float* __restrict__ Mpart, float* __restrict__ Mmat) {
  int j0 = u * 64;
  int jj = tid & 63, sub = tid >> 6;
  const float* mp = Mpart + (size_t)(sub * 32) * (DIM * DIM) + j0;
  float s = 0.f;
  #pragma unroll 4
  for (int k = 0; k < 32; ++k) s += mp[(size_t)k * (DIM * DIM) + jj];
  smem[sub * 64 + jj] = s;
  __syncthreads();
  if (tid < 64)
    Mmat[j0 + tid] = smem[tid] + smem[64 + tid] + smem[128 + tid] + smem[192 + tid];
}

// scan (256 thr): offs = exclusive scan of gcnt (=deg-1); dis = rsqrt(deg)
static __device__ void ph_scan(int tid, int* wsum,
    const int* __restrict__ gcnt, int* __restrict__ offs, float* __restrict__ dis) {
  int lane = tid & 63, wave = tid >> 6;
  const int4* g4 = (const int4*)gcnt;
  int s = 0;
  #pragma unroll
  for (int i = 0; i < 8; ++i) { int4 v = g4[tid * 8 + i]; s += v.x + v.y + v.z + v.w; }
  int sc = s;
  #pragma unroll
  for (int off = 1; off < 64; off <<= 1) {
    int v = __shfl_up(sc, off);
    if (lane >= off) sc += v;
  }
  if (lane == 63) wsum[wave] = sc;
  __syncthreads();
  if (wave == 0 && lane < 4) {
    int v = wsum[lane];
    #pragma unroll
    for (int off = 1; off < 4; off <<= 1) {
      int u = __shfl_up(v, off);
      if (lane >= off) v += u;
    }
    wsum[lane] = v;
  }
  __syncthreads();
  int run = (wave ? wsum[wave - 1] : 0) + sc - s;
  #pragma unroll
  for (int i = 0; i < 8; ++i) {
    int4 v = g4[tid * 8 + i];
    int4 o;
    o.x = run; run += v.x;
    o.y = run; run += v.y;
    o.z = run; run += v.z;
    o.w = run; run += v.w;
    *(int4*)&offs[tid * 32 + i * 4] = o;
    float4 d;
    d.x = rsqrtf((float)(v.x + 1)); d.y = rsqrtf((float)(v.y + 1));
    d.z = rsqrtf((float)(v.z + 1)); d.w = rsqrtf((float)(v.w + 1));
    *(float4*)&dis[tid * 32 + i * 4] = d;
  }
}

// GEMM unit u (128 thr): RWB=32 rows; thread = 4 rows x (4+4 split cols) x {W,M}.
// wave = 4 ry x 16 tx -> W/M fragment reads are 16 addr x 4 broadcast = 2-way
// conflict (free); xs padded to stride 132 keeps xf reads 2-way. 1.25 B/FMA.
static __device__ void ph_gemm(int u, int tid, float* smem,
    const float* __restrict__ x, const float* __restrict__ W,
    const float* __restrict__ Mmat, const float* __restrict__ rinv,
    const float* __restrict__ dis, unsigned short* __restrict__ xws,
    float* __restrict__ att) {
  float* xs  = smem;                    // 32*132 = 4224 f
  float* Wl  = smem + 4224;             // 2048 f
  float* Ml  = smem + 6272;             // 2048 f
  float* rvs = smem + 8320;             // 32 f
  float* dss = smem + 8352;             // 32 f
  int row0 = u * RWB;
  #pragma unroll
  for (int i = 0; i < 8; ++i) {
    int fidx = i * 128 + tid;           // float4 index 0..1023
    int row = fidx >> 5, c4 = fidx & 31;
    ((float4*)(xs + row * XSS))[c4] =
        ((const float4*)(x + (size_t)(row0 + row) * DIM))[c4];
  }
  if (tid < RWB) { rvs[tid] = rinv[row0 + tid]; dss[tid] = dis[row0 + tid]; }

  int ry = tid >> 4, tx = tid & 15;
  int r0 = ry * 4;
  float4 aw0[4], aw1[4], am0[4], am1[4];
  #pragma unroll
  for (int j = 0; j < 4; ++j) {
    aw0[j] = make_float4(0,0,0,0); aw1[j] = make_float4(0,0,0,0);
    am0[j] = make_float4(0,0,0,0); am1[j] = make_float4(0,0,0,0);
  }

  for (int kk = 0; kk < DIM; kk += BK) {
    __syncthreads();
    const float4* Ws = (const float4*)(W + (size_t)kk * DIM);
    const float4* Ms = (const float4*)(Mmat + (size_t)kk * DIM);
    #pragma unroll
    for (int i = 0; i < 4; ++i) {
      ((float4*)Wl)[tid + 128 * i] = Ws[tid + 128 * i];
      ((float4*)Ml)[tid + 128 * i] = Ms[tid + 128 * i];
    }
    __syncthreads();
    #pragma unroll
    for (int k4 = 0; k4 < BK; k4 += 4) {
      float4 xf[4];
      #pragma unroll
      for (int j = 0; j < 4; ++j)
        xf[j] = *(const float4*)&xs[(r0 + j) * XSS + kk + k4];
      #pragma unroll
      for (int k = 0; k < 4; ++k) {
        float4 wv0 = *(const float4*)&Wl[(k4 + k) * DIM + tx * 4];
        float4 wv1 = *(const float4*)&Wl[(k4 + k) * DIM + 64 + tx * 4];
        float4 mv0 = *(const float4*)&Ml[(k4 + k) * DIM + tx * 4];
        float4 mv1 = *(const float4*)&Ml[(k4 + k) * DIM + 64 + tx * 4];
        #pragma unroll
        for (int j = 0; j < 4; ++j) {
          float xv = ((const float*)&xf[j])[k];
          aw0[j].x += xv * wv0.x; aw0[j].y += xv * wv0.y;
          aw0[j].z += xv * wv0.z; aw0[j].w += xv * wv0.w;
          aw1[j].x += xv * wv1.x; aw1[j].y += xv * wv1.y;
          aw1[j].z += xv * wv1.z; aw1[j].w += xv * wv1.w;
          am0[j].x += xv * mv0.x; am0[j].y += xv * mv0.y;
          am0[j].z += xv * mv0.z; am0[j].w += xv * mv0.w;
          am1[j].x += xv * mv1.x; am1[j].y += xv * mv1.y;
          am1[j].z += xv * mv1.z; am1[j].w += xv * mv1.w;
        }
      }
    }
  }
  #pragma unroll
  for (int j = 0; j < 4; ++j) {
    int row = row0 + r0 + j;
    float rv = rvs[r0 + j], ds = dss[r0 + j];
    size_t oA = (size_t)row * DIM + tx * 4;
    size_t oB = oA + 64;
    ushort4 wbA, wbB;
    wbA.x = f2bf(aw0[j].x * ds); wbA.y = f2bf(aw0[j].y * ds);
    wbA.z = f2bf(aw0[j].z * ds); wbA.w = f2bf(aw0[j].w * ds);
    wbB.x = f2bf(aw1[j].x * ds); wbB.y = f2bf(aw1[j].y * ds);
    wbB.z = f2bf(aw1[j].z * ds); wbB.w = f2bf(aw1[j].w * ds);
    *(ushort4*)&xws[oA] = wbA;
    *(ushort4*)&xws[oB] = wbB;
    float4 gA, gB;
    gA.x = 1.0f / (1.0f + __expf(-am0[j].x * rv));
    gA.y = 1.0f / (1.0f + __expf(-am0[j].y * rv));
    gA.z = 1.0f / (1.0f + __expf(-am0[j].z * rv));
    gA.w = 1.0f / (1.0f + __expf(-am0[j].w * rv));
    gB.x = 1.0f / (1.0f + __expf(-am1[j].x * rv));
    gB.y = 1.0f / (1.0f + __expf(-am1[j].y * rv));
    gB.z = 1.0f / (1.0f + __expf(-am1[j].z * rv));
    gB.w = 1.0f / (1.0f + __expf(-am1[j].w * rv));
    *(float4*)&att[oA] = gA;
    *(float4*)&att[oB] = gB;
  }
}

// placement chunk u (128 thr): pos = offs[tgt] + slot  (no atomics)
static __device__ void ph_place(int u, int tid,
    const int* __restrict__ ei, const int* __restrict__ offs,
    const int* __restrict__ slot, int* __restrict__ sorted) {
  int e0 = u * PEB + tid * 16;
  #pragma unroll
  for (int i = 0; i < 4; ++i) {
    int4 sv = *(const int4*)(ei + e0 + i * 4);          // sources
    int4 cv = *(const int4*)(ei + NE + e0 + i * 4);     // targets
    int4 sl = *(const int4*)(slot + e0 + i * 4);
    sorted[offs[cv.x] + sl.x] = sv.x;
    sorted[offs[cv.y] + sl.y] = sv.y;
    sorted[offs[cv.z] + sl.z] = sv.z;
    sorted[offs[cv.w] + sl.w] = sv.w;
  }
}

// ==================== kernels ====================
__global__ __launch_bounds__(256) void k_pA(const float* __restrict__ x,
    const int* __restrict__ ei, float* __restrict__ rinv,
    float* __restrict__ Mpart, int* __restrict__ gcnt, int* __restrict__ slot) {
  __shared__ float smem[SMEMF];
  int u = blockIdx.x, tid = threadIdx.x;
  if (u < XB) ph_xtx(u, tid, smem, x, rinv, Mpart);
  else        ph_hist(u - XB, tid, (int*)smem, ei, gcnt, slot);
}
__global__ __launch_bounds__(256) void k_pB(const float* __restrict__ Mpart,
    float* __restrict__ Mmat, const int* __restrict__ gcnt,
    int* __restrict__ offs, float* __restrict__ dis) {
  __shared__ float smem[SMEMF];
  int u = blockIdx.x, tid = threadIdx.x;
  if (u < 256) ph_mred(u, tid, smem, Mpart, Mmat);
  else         ph_scan(tid, (int*)smem, gcnt, offs, dis);
}
__global__ __launch_bounds__(128) void k_pC(const float* __restrict__ x,
    const float* __restrict__ W, const float* __restrict__ Mmat,
    const float* __restrict__ rinv, const float* __restrict__ dis,
    const int* __restrict__ ei, const int* __restrict__ offs,
    const int* __restrict__ slot, int* __restrict__ sorted,
    unsigned short* __restrict__ xws, float* __restrict__ att) {
  __shared__ float smem[SMEMF];
  int u = blockIdx.x, tid = threadIdx.x;
  if (u < NN / RWB) ph_gemm(u, tid, smem, x, W, Mmat, rinv, dis, xws, att);
  else              ph_place(u - NN / RWB, tid, ei, offs, slot, sorted);
}
// gather: one node per 64-thread wave-block; uint (ushort2) loads; unroll 8
__global__ __launch_bounds__(64) void k_pD(const int* __restrict__ offs,
    const int* __restrict__ gcnt, const float* __restrict__ dis,
    const unsigned short* __restrict__ xws, const float* __restrict__ att,
    const float* __restrict__ bias, const int* __restrict__ sorted,
    float* __restrict__ out) {
  int c = blockIdx.x, t = threadIdx.x;
  int base = offs[c];
  int cnt  = gcnt[c];                            // deg-1
  const unsigned int* xw2 = (const unsigned int*)xws;
  unsigned int sv = xw2[(size_t)c * 64 + t];     // self-loop term
  float acc0 = bf2f(sv & 0xffffu), acc1 = bf2f(sv >> 16);
  int k = 0;
  for (; k + 8 <= cnt; k += 8) {
    int4 i0 = *(const int4*)(sorted + base + k);
    int4 i1 = *(const int4*)(sorted + base + k + 4);
    unsigned int v0 = xw2[(size_t)i0.x * 64 + t];
    unsigned int v1 = xw2[(size_t)i0.y * 64 + t];
    unsigned int v2 = xw2[(size_t)i0.z * 64 + t];
    unsigned int v3 = xw2[(size_t)i0.w * 64 + t];
    unsigned int v4 = xw2[(size_t)i1.x * 64 + t];
    unsigned int v5 = xw2[(size_t)i1.y * 64 + t];
    unsigned int v6 = xw2[(size_t)i1.z * 64 + t];
    unsigned int v7 = xw2[(size_t)i1.w * 64 + t];
    acc0 += bf2f(v0 & 0xffffu) + bf2f(v1 & 0xffffu) + bf2f(v2 & 0xffffu) + bf2f(v3 & 0xffffu)
          + bf2f(v4 & 0xffffu) + bf2f(v5 & 0xffffu) + bf2f(v6 & 0xffffu) + bf2f(v7 & 0xffffu);
    acc1 += bf2f(v0 >> 16) + bf2f(v1 >> 16) + bf2f(v2 >> 16) + bf2f(v3 >> 16)
          + bf2f(v4 >> 16) + bf2f(v5 >> 16) + bf2f(v6 >> 16) + bf2f(v7 >> 16);
  }
  for (; k + 4 <= cnt; k += 4) {
    int4 i0 = *(const int4*)(sorted + base + k);
    unsigned int v0 = xw2[(size_t)i0.x * 64 + t];
    unsigned int v1 = xw2[(size_t)i0.y * 64 + t];
    unsigned int v2 = xw2[(size_t)i0.z * 64 + t];
    unsigned int v3 = xw2[(size_t)i0.w * 64 + t];
    acc0 += bf2f(v0 & 0xffffu) + bf2f(v1 & 0xffffu) + bf2f(v2 & 0xffffu) + bf2f(v3 & 0xffffu);
    acc1 += bf2f(v0 >> 16) + bf2f(v1 >> 16) + bf2f(v2 >> 16) + bf2f(v3 >> 16);
  }
  for (; k < cnt; ++k) {
    unsigned int v = xw2[(size_t)sorted[base + k] * 64 + t];
    acc0 += bf2f(v & 0xffffu);
    acc1 += bf2f(v >> 16);
  }
  float dc = dis[c];
  float2 at = ((const float2*)att)[(size_t)c * 64 + t];
  float2 bs = ((const float2*)bias)[t];
  float2 o;
  o.x = (acc0 * dc + bs.x) * at.x;
  o.y = (acc1 * dc + bs.y) * at.y;
  ((float2*)out)[(size_t)c * 64 + t] = o;
}

// ---------------------------------------------------------------------- launch
extern "C" void kernel_launch(void* const* d_in, const int* in_sizes, int n_in,
                              void* d_out, int out_size, void* d_ws, size_t ws_size,
                              hipStream_t stream) {
  const float* x  = (const float*)d_in[0];
  const int*   ei = (const int*)  d_in[1];
  const float* W  = (const float*)d_in[2];
  const float* b  = (const float*)d_in[3];
  float* out = (float*)d_out;

  // ws layout (~15.5 MB)
  unsigned short* xws = (unsigned short*)d_ws;        // NN*DIM bf16
  float* att   = (float*)(xws + (size_t)NN * DIM);    // NN*DIM
  float* Mpart = att + (size_t)NN * DIM;              // XB*DIM*DIM
  float* Mmat  = Mpart + (size_t)XB * DIM * DIM;      // DIM*DIM
  float* rinv  = Mmat + DIM * DIM;                    // NN
  float* dis   = rinv + NN;                           // NN
  int*   gcnt  = (int*)(dis + NN);                    // NN (zeroed below)
  int*   offs  = gcnt + NN;                           // NN
  int*   slot  = offs + NN;                           // NE
  int*   sorted= slot + NE;                           // NE

  hipMemsetAsync(gcnt, 0, NN * sizeof(int), stream);

  k_pA<<<XB + HBH, 256, 0, stream>>>(x, ei, rinv, Mpart, gcnt, slot);
  k_pB<<<257, 256, 0, stream>>>(Mpart, Mmat, gcnt, offs, dis);
  k_pC<<<NN / RWB + PBP, 128, 0, stream>>>(x, W, Mmat, rinv, dis, ei, offs,
                                           slot, sorted, xws, att);
  k_pD<<<NN, 64, 0, stream>>>(offs, gcnt, dis, xws, att, b, sorted, out);
}

// Round 12
// 112.158 us; speedup vs baseline: 2.8649x; 1.0376x over previous
//
#include <hip/hip_runtime.h>
#include <math.h>

#define NN   8192
#define DIM  128
#define NE   262144
#define XB   64           // xtx units (128 rows each, staged in 2 halves)
#define HBH  64           // histogram chunks (256-thr, 4096 edges)
#define HEB  (NE / HBH)
#define PBP  64           // placement chunks (256-thr, 4096 edges)
#define PEB  (NE / PBP)
#define RWB  32           // rows per GEMM unit (256 thr, 4 rows/thread)
#define BK   16           // k-chunk rows of W/M staged in LDS
#define XSS  132          // padded xs row stride in kC
#define SMEMF 8448

// bf16 via explicit bit math (this ROCm's __hip_bfloat16 lacks .data)
static __device__ __forceinline__ unsigned short f2bf(float f) {
  unsigned int u = __float_as_uint(f);
  return (unsigned short)((u + 0x7FFFu + ((u >> 16) & 1u)) >> 16);   // RNE
}
static __device__ __forceinline__ float bf2f(unsigned int h) {
  return __uint_as_float(h << 16);
}

// ==================== phase unit functions ====================

// xtx unit u (256 thr): 128 rows in two 64-row stagings; acc carried across.
// Halves Mpart traffic vs 64-row units. Fragments split 4+4 -> 2-way = free.
static __device__ void ph_xtx(int u, int tid, float* smem,
    const float* __restrict__ x, float* __restrict__ rinv,
    float* __restrict__ Mpart) {
  float* xs  = smem;
  float* rvs = smem + 64 * DIM;
  int ty = tid >> 4, tx = tid & 15;
  float acc[8][8];
  #pragma unroll
  for (int i = 0; i < 8; ++i)
    #pragma unroll
    for (int j = 0; j < 8; ++j) acc[i][j] = 0.f;

  for (int half = 0; half < 2; ++half) {
    int row0 = u * 128 + half * 64;
    const float4* xsrc = (const float4*)(x + (size_t)row0 * DIM);
    float4* xdst = (float4*)xs;
    #pragma unroll
    for (int i = 0; i < 8; ++i) xdst[tid + 256 * i] = xsrc[tid + 256 * i];
    __syncthreads();
    int rr = tid >> 2, q = tid & 3;
    const float4* xr = (const float4*)&xs[rr * DIM + q * 32];
    float ss = 0.f;
    #pragma unroll
    for (int i = 0; i < 8; ++i) {
      float4 v = xr[i];
      ss += v.x * v.x + v.y * v.y + v.z * v.z + v.w * v.w;
    }
    ss += __shfl_xor(ss, 1);
    ss += __shfl_xor(ss, 2);
    if (q == 0) { float rv = 1.0f / sqrtf(ss); rvs[rr] = rv; rinv[row0 + rr] = rv; }
    __syncthreads();

    #pragma unroll 2
    for (int r = 0; r < 64; ++r) {
      float4 a0 = *(const float4*)&xs[r * DIM + ty * 4];
      float4 a1 = *(const float4*)&xs[r * DIM + 64 + ty * 4];
      float4 b0 = *(const float4*)&xs[r * DIM + tx * 4];
      float4 b1 = *(const float4*)&xs[r * DIM + 64 + tx * 4];
      float rv = rvs[r];
      float a[8] = {a0.x * rv, a0.y * rv, a0.z * rv, a0.w * rv,
                    a1.x * rv, a1.y * rv, a1.z * rv, a1.w * rv};
      float b[8] = {b0.x, b0.y, b0.z, b0.w, b1.x, b1.y, b1.z, b1.w};
      #pragma unroll
      for (int i = 0; i < 8; ++i)
        #pragma unroll
        for (int j = 0; j < 8; ++j) acc[i][j] += a[i] * b[j];
    }
    __syncthreads();   // xs/rvs reused next half
  }
  float* o = Mpart + (size_t)u * (DIM * DIM);
  #pragma unroll
  for (int i = 0; i < 8; ++i) {
    int row = (i < 4) ? (ty * 4 + i) : (64 + ty * 4 + (i - 4));
    *(float4*)&o[row * DIM + tx * 4]      = make_float4(acc[i][0], acc[i][1], acc[i][2], acc[i][3]);
    *(float4*)&o[row * DIM + 64 + tx * 4] = make_float4(acc[i][4], acc[i][5], acc[i][6], acc[i][7]);
  }
}

// hist chunk h (256 thr): LDS histogram; 1 global atomic per TOUCHED bin
// claims the chunk's base; per-edge final slot = base + local rank.
static __device__ void ph_hist(int h, int tid, int* ldeg,
    const int* __restrict__ ei, int* __restrict__ gcnt, int* __restrict__ slot) {
  int4* lz = (int4*)ldeg;
  #pragma unroll
  for (int i = tid; i < NN / 4; i += 256) lz[i] = make_int4(0, 0, 0, 0);
  __syncthreads();
  int e0 = h * HEB + tid * 16;
  int4 c0 = *(const int4*)(ei + NE + e0);       // targets
  int4 c1 = *(const int4*)(ei + NE + e0 + 4);
  int4 c2 = *(const int4*)(ei + NE + e0 + 8);
  int4 c3 = *(const int4*)(ei + NE + e0 + 12);
  int r0  = atomicAdd(&ldeg[c0.x], 1);
  int r1  = atomicAdd(&ldeg[c0.y], 1);
  int r2  = atomicAdd(&ldeg[c0.z], 1);
  int r3  = atomicAdd(&ldeg[c0.w], 1);
  int r4  = atomicAdd(&ldeg[c1.x], 1);
  int r5  = atomicAdd(&ldeg[c1.y], 1);
  int r6  = atomicAdd(&ldeg[c1.z], 1);
  int r7  = atomicAdd(&ldeg[c1.w], 1);
  int r8  = atomicAdd(&ldeg[c2.x], 1);
  int r9  = atomicAdd(&ldeg[c2.y], 1);
  int r10 = atomicAdd(&ldeg[c2.z], 1);
  int r11 = atomicAdd(&ldeg[c2.w], 1);
  int r12 = atomicAdd(&ldeg[c3.x], 1);
  int r13 = atomicAdd(&ldeg[c3.y], 1);
  int r14 = atomicAdd(&ldeg[c3.z], 1);
  int r15 = atomicAdd(&ldeg[c3.w], 1);
  __syncthreads();
  int binb = tid * 32;
  #pragma unroll
  for (int i = 0; i < 8; ++i) {
    int4 v = *(int4*)&ldeg[binb + i * 4];
    if (v.x) ldeg[binb + i * 4 + 0] = atomicAdd(&gcnt[binb + i * 4 + 0], v.x);
    if (v.y) ldeg[binb + i * 4 + 1] = atomicAdd(&gcnt[binb + i * 4 + 1], v.y);
    if (v.z) ldeg[binb + i * 4 + 2] = atomicAdd(&gcnt[binb + i * 4 + 2], v.z);
    if (v.w) ldeg[binb + i * 4 + 3] = atomicAdd(&gcnt[binb + i * 4 + 3], v.w);
  }
  __syncthreads();
  int4 s0 = make_int4(ldeg[c0.x] + r0,  ldeg[c0.y] + r1,  ldeg[c0.z] + r2,  ldeg[c0.w] + r3);
  int4 s1 = make_int4(ldeg[c1.x] + r4,  ldeg[c1.y] + r5,  ldeg[c1.z] + r6,  ldeg[c1.w] + r7);
  int4 s2 = make_int4(ldeg[c2.x] + r8,  ldeg[c2.y] + r9,  ldeg[c2.z] + r10, ldeg[c2.w] + r11);
  int4 s3 = make_int4(ldeg[c3.x] + r12, ldeg[c3.y] + r13, ldeg[c3.z] + r14, ldeg[c3.w] + r15);
  *(int4*)(slot + e0)      = s0;
  *(int4*)(slot + e0 + 4)  = s1;
  *(int4*)(slot + e0 + 8)  = s2;
  *(int4*)(slot + e0 + 12) = s3;
}

// M-reduce unit u (256 thr): sum 64 partials for 64 entries, split-K via LDS
static __device__ void ph_mred(int u, int tid, float* smem,
    const float* __restrict__ Mpart, float* __restrict__ Mmat) {
  int j0 = u * 64;
  int jj = tid & 63, sub = tid >> 6;
  const float* mp = Mpart + (size_t)(sub * 16) * (DIM * DIM) + j0;
  float s = 0.f;
  #pragma unroll 4
  for (int k = 0; k < 16; ++k) s += mp[(size_t)k * (DIM * DIM) + jj];
  smem[sub * 64 + jj] = s;
  __syncthreads();
  if (tid < 64)
    Mmat[j0 + tid] = smem[tid] + smem[64 + tid] + smem[128 + tid] + smem[192 + tid];
}

// scan (256 thr): offs = exclusive scan of gcnt (=deg-1); dis = rsqrt(deg)
static __device__ void ph_scan(int tid, int* wsum,
    const int* __restrict__ gcnt, int* __restrict__ offs, float* __restrict__ dis) {
  int lane = tid & 63, wave = tid >> 6;
  const int4* g4 = (const int4*)gcnt;
  int s = 0;
  #pragma unroll
  for (int i = 0; i < 8; ++i) { int4 v = g4[tid * 8 + i]; s += v.x + v.y + v.z + v.w; }
  int sc = s;
  #pragma unroll
  for (int off = 1; off < 64; off <<= 1) {
    int v = __shfl_up(sc, off);
    if (lane >= off) sc += v;
  }
  if (lane == 63) wsum[wave] = sc;
  __syncthreads();
  if (wave == 0 && lane < 4) {
    int v = wsum[lane];
    #pragma unroll
    for (int off = 1; off < 4; off <<= 1) {
      int u = __shfl_up(v, off);
      if (lane >= off) v += u;
    }
    wsum[lane] = v;
  }
  __syncthreads();
  int run = (wave ? wsum[wave - 1] : 0) + sc - s;
  #pragma unroll
  for (int i = 0; i < 8; ++i) {
    int4 v = g4[tid * 8 + i];
    int4 o;
    o.x = run; run += v.x;
    o.y = run; run += v.y;
    o.z = run; run += v.z;
    o.w = run; run += v.w;
    *(int4*)&offs[tid * 32 + i * 4] = o;
    float4 d;
    d.x = rsqrtf((float)(v.x + 1)); d.y = rsqrtf((float)(v.y + 1));
    d.z = rsqrtf((float)(v.z + 1)); d.w = rsqrtf((float)(v.w + 1));
    *(float4*)&dis[tid * 32 + i * 4] = d;
  }
}

// GEMM unit u (256 thr): RWB=32 rows; thread = 4 rows x 4 cols x {W,M}.
// 256 blocks x 4 waves = 1024 waves = 1/SIMD (r10's 128-thr shape left half
// the SIMDs idle). wv/mv reads: 32 addr x 2-way broadcast = free.
static __device__ void ph_gemm(int u, int tid, float* smem,
    const float* __restrict__ x, const float* __restrict__ W,
    const float* __restrict__ Mmat, const float* __restrict__ rinv,
    const float* __restrict__ dis, unsigned short* __restrict__ xws,
    float* __restrict__ att) {
  float* xs  = smem;                    // 32*132 = 4224 f
  float* Wl  = smem + 4224;             // 2048 f
  float* Ml  = smem + 6272;             // 2048 f
  float* rvs = smem + 8320;             // 32 f
  float* dss = smem + 8352;             // 32 f
  int row0 = u * RWB;
  #pragma unroll
  for (int i = 0; i < 4; ++i) {
    int fidx = i * 256 + tid;           // float4 index 0..1023
    int row = fidx >> 5, c4 = fidx & 31;
    ((float4*)(xs + row * XSS))[c4] =
        ((const float4*)(x + (size_t)(row0 + row) * DIM))[c4];
  }
  if (tid < RWB) { rvs[tid] = rinv[row0 + tid]; dss[tid] = dis[row0 + tid]; }

  int ry = tid >> 5, tx = tid & 31;
  int r0 = ry * 4;
  float4 aw[4], am[4];
  #pragma unroll
  for (int j = 0; j < 4; ++j) { aw[j] = make_float4(0,0,0,0); am[j] = make_float4(0,0,0,0); }

  for (int kk = 0; kk < DIM; kk += BK) {
    __syncthreads();
    const float4* Ws = (const float4*)(W + (size_t)kk * DIM);
    const float4* Ms = (const float4*)(Mmat + (size_t)kk * DIM);
    ((float4*)Wl)[tid]       = Ws[tid];
    ((float4*)Wl)[tid + 256] = Ws[tid + 256];
    ((float4*)Ml)[tid]       = Ms[tid];
    ((float4*)Ml)[tid + 256] = Ms[tid + 256];
    __syncthreads();
    #pragma unroll
    for (int k4 = 0; k4 < BK; k4 += 4) {
      float4 xf[4];
      #pragma unroll
      for (int j = 0; j < 4; ++j)
        xf[j] = *(const float4*)&xs[(r0 + j) * XSS + kk + k4];
      #pragma unroll
      for (int k = 0; k < 4; ++k) {
        float4 wv = *(const float4*)&Wl[(k4 + k) * DIM + tx * 4];
        float4 mv = *(const float4*)&Ml[(k4 + k) * DIM + tx * 4];
        #pragma unroll
        for (int j = 0; j < 4; ++j) {
          float xv = ((const float*)&xf[j])[k];
          aw[j].x += xv * wv.x; aw[j].y += xv * wv.y;
          aw[j].z += xv * wv.z; aw[j].w += xv * wv.w;
          am[j].x += xv * mv.x; am[j].y += xv * mv.y;
          am[j].z += xv * mv.z; am[j].w += xv * mv.w;
        }
      }
    }
  }
  #pragma unroll
  for (int j = 0; j < 4; ++j) {
    int row = row0 + r0 + j;
    float rv = rvs[r0 + j], ds = dss[r0 + j];
    size_t o = (size_t)row * DIM + tx * 4;
    ushort4 wb;
    wb.x = f2bf(aw[j].x * ds); wb.y = f2bf(aw[j].y * ds);
    wb.z = f2bf(aw[j].z * ds); wb.w = f2bf(aw[j].w * ds);
    *(ushort4*)&xws[o] = wb;
    float4 g;
    g.x = 1.0f / (1.0f + __expf(-am[j].x * rv));
    g.y = 1.0f / (1.0f + __expf(-am[j].y * rv));
    g.z = 1.0f / (1.0f + __expf(-am[j].z * rv));
    g.w = 1.0f / (1.0f + __expf(-am[j].w * rv));
    *(float4*)&att[o] = g;
  }
}

// placement chunk u (256 thr): pos = offs[tgt] + slot  (no atomics)
static __device__ void ph_place(int u, int tid,
    const int* __restrict__ ei, const int* __restrict__ offs,
    const int* __restrict__ slot, int* __restrict__ sorted) {
  int e0 = u * PEB + tid * 16;
  #pragma unroll
  for (int i = 0; i < 4; ++i) {
    int4 sv = *(const int4*)(ei + e0 + i * 4);          // sources
    int4 cv = *(const int4*)(ei + NE + e0 + i * 4);     // targets
    int4 sl = *(const int4*)(slot + e0 + i * 4);
    sorted[offs[cv.x] + sl.x] = sv.x;
    sorted[offs[cv.y] + sl.y] = sv.y;
    sorted[offs[cv.z] + sl.z] = sv.z;
    sorted[offs[cv.w] + sl.w] = sv.w;
  }
}

// ==================== kernels ====================
__global__ __launch_bounds__(256) void k_pA(const float* __restrict__ x,
    const int* __restrict__ ei, float* __restrict__ rinv,
    float* __restrict__ Mpart, int* __restrict__ gcnt, int* __restrict__ slot) {
  __shared__ float smem[SMEMF];
  int u = blockIdx.x, tid = threadIdx.x;
  if (u < XB) ph_xtx(u, tid, smem, x, rinv, Mpart);
  else        ph_hist(u - XB, tid, (int*)smem, ei, gcnt, slot);
}
__global__ __launch_bounds__(256) void k_pB(const float* __restrict__ Mpart,
    float* __restrict__ Mmat, const int* __restrict__ gcnt,
    int* __restrict__ offs, float* __restrict__ dis) {
  __shared__ float smem[SMEMF];
  int u = blockIdx.x, tid = threadIdx.x;
  if (u < 256) ph_mred(u, tid, smem, Mpart, Mmat);
  else         ph_scan(tid, (int*)smem, gcnt, offs, dis);
}
__global__ __launch_bounds__(256) void k_pC(const float* __restrict__ x,
    const float* __restrict__ W, const float* __restrict__ Mmat,
    const float* __restrict__ rinv, const float* __restrict__ dis,
    const int* __restrict__ ei, const int* __restrict__ offs,
    const int* __restrict__ slot, int* __restrict__ sorted,
    unsigned short* __restrict__ xws, float* __restrict__ att) {
  __shared__ float smem[SMEMF];
  int u = blockIdx.x, tid = threadIdx.x;
  if (u < NN / RWB) ph_gemm(u, tid, smem, x, W, Mmat, rinv, dis, xws, att);
  else              ph_place(u - NN / RWB, tid, ei, offs, slot, sorted);
}
// gather: one node per 64-thread wave-block; uint (ushort2) loads; unroll 8
__global__ __launch_bounds__(64) void k_pD(const int* __restrict__ offs,
    const int* __restrict__ gcnt, const float* __restrict__ dis,
    const unsigned short* __restrict__ xws, const float* __restrict__ att,
    const float* __restrict__ bias, const int* __restrict__ sorted,
    float* __restrict__ out) {
  int c = blockIdx.x, t = threadIdx.x;
  int base = offs[c];
  int cnt  = gcnt[c];                            // deg-1
  const unsigned int* xw2 = (const unsigned int*)xws;
  unsigned int sv = xw2[(size_t)c * 64 + t];     // self-loop term
  float acc0 = bf2f(sv & 0xffffu), acc1 = bf2f(sv >> 16);
  int k = 0;
  for (; k + 8 <= cnt; k += 8) {
    int4 i0 = *(const int4*)(sorted + base + k);
    int4 i1 = *(const int4*)(sorted + base + k + 4);
    unsigned int v0 = xw2[(size_t)i0.x * 64 + t];
    unsigned int v1 = xw2[(size_t)i0.y * 64 + t];
    unsigned int v2 = xw2[(size_t)i0.z * 64 + t];
    unsigned int v3 = xw2[(size_t)i0.w * 64 + t];
    unsigned int v4 = xw2[(size_t)i1.x * 64 + t];
    unsigned int v5 = xw2[(size_t)i1.y * 64 + t];
    unsigned int v6 = xw2[(size_t)i1.z * 64 + t];
    unsigned int v7 = xw2[(size_t)i1.w * 64 + t];
    acc0 += bf2f(v0 & 0xffffu) + bf2f(v1 & 0xffffu) + bf2f(v2 & 0xffffu) + bf2f(v3 & 0xffffu)
          + bf2f(v4 & 0xffffu) + bf2f(v5 & 0xffffu) + bf2f(v6 & 0xffffu) + bf2f(v7 & 0xffffu);
    acc1 += bf2f(v0 >> 16) + bf2f(v1 >> 16) + bf2f(v2 >> 16) + bf2f(v3 >> 16)
          + bf2f(v4 >> 16) + bf2f(v5 >> 16) + bf2f(v6 >> 16) + bf2f(v7 >> 16);
  }
  for (; k + 4 <= cnt; k += 4) {
    int4 i0 = *(const int4*)(sorted + base + k);
    unsigned int v0 = xw2[(size_t)i0.x * 64 + t];
    unsigned int v1 = xw2[(size_t)i0.y * 64 + t];
    unsigned int v2 = xw2[(size_t)i0.z * 64 + t];
    unsigned int v3 = xw2[(size_t)i0.w * 64 + t];
    acc0 += bf2f(v0 & 0xffffu) + bf2f(v1 & 0xffffu) + bf2f(v2 & 0xffffu) + bf2f(v3 & 0xffffu);
    acc1 += bf2f(v0 >> 16) + bf2f(v1 >> 16) + bf2f(v2 >> 16) + bf2f(v3 >> 16);
  }
  for (; k < cnt; ++k) {
    unsigned int v = xw2[(size_t)sorted[base + k] * 64 + t];
    acc0 += bf2f(v & 0xffffu);
    acc1 += bf2f(v >> 16);
  }
  float dc = dis[c];
  float2 at = ((const float2*)att)[(size_t)c * 64 + t];
  float2 bs = ((const float2*)bias)[t];
  float2 o;
  o.x = (acc0 * dc + bs.x) * at.x;
  o.y = (acc1 * dc + bs.y) * at.y;
  ((float2*)out)[(size_t)c * 64 + t] = o;
}

// ---------------------------------------------------------------------- launch
extern "C" void kernel_launch(void* const* d_in, const int* in_sizes, int n_in,
                              void* d_out, int out_size, void* d_ws, size_t ws_size,
                              hipStream_t stream) {
  const float* x  = (const float*)d_in[0];
  const int*   ei = (const int*)  d_in[1];
  const float* W  = (const float*)d_in[2];
  const float* b  = (const float*)d_in[3];
  float* out = (float*)d_out;

  // ws layout (~11.5 MB)
  unsigned short* xws = (unsigned short*)d_ws;        // NN*DIM bf16
  float* att   = (float*)(xws + (size_t)NN * DIM);    // NN*DIM
  float* Mpart = att + (size_t)NN * DIM;              // XB*DIM*DIM (4 MB)
  float* Mmat  = Mpart + (size_t)XB * DIM * DIM;      // DIM*DIM
  float* rinv  = Mmat + DIM * DIM;                    // NN
  float* dis   = rinv + NN;                           // NN
  int*   gcnt  = (int*)(dis + NN);                    // NN (zeroed below)
  int*   offs  = gcnt + NN;                           // NN
  int*   slot  = offs + NN;                           // NE
  int*   sorted= slot + NE;                           // NE

  hipMemsetAsync(gcnt, 0, NN * sizeof(int), stream);

  k_pA<<<XB + HBH, 256, 0, stream>>>(x, ei, rinv, Mpart, gcnt, slot);
  k_pB<<<257, 256, 0, stream>>>(Mpart, Mmat, gcnt, offs, dis);
  k_pC<<<NN / RWB + PBP, 256, 0, stream>>>(x, W, Mmat, rinv, dis, ei, offs,
                                           slot, sorted, xws, att);
  k_pD<<<NN, 64, 0, stream>>>(offs, gcnt, dis, xws, att, b, sorted, out);
}

// Round 13
// 111.476 us; speedup vs baseline: 2.8824x; 1.0061x over previous
//
#include <hip/hip_runtime.h>
#include <math.h>

#define NN   8192
#define DIM  128
#define NE   262144
#define XB   128          // xtx units (64 rows each) — 128 units keeps kA's grid fat
#define HBH  64           // histogram chunks (256-thr, 4096 edges)
#define HEB  (NE / HBH)
#define PBP  64           // placement chunks (256-thr, 4096 edges)
#define PEB  (NE / PBP)
#define RWB  32           // rows per GEMM unit (256 thr, 4 rows/thread)
#define BK   16           // k-chunk rows of W/M staged in LDS
#define XSS  132          // padded xs row stride in kC
#define SMEMF 8448

// bf16 via explicit bit math (this ROCm's __hip_bfloat16 lacks .data)
static __device__ __forceinline__ unsigned short f2bf(float f) {
  unsigned int u = __float_as_uint(f);
  return (unsigned short)((u + 0x7FFFu + ((u >> 16) & 1u)) >> 16);   // RNE
}
static __device__ __forceinline__ float bf2f(unsigned int h) {
  return __uint_as_float(h << 16);
}

// ==================== phase unit functions ====================

// xtx unit u (256 thr): 64 rows staged once; write rinv; emit Mpart[u].
// 128 units -> 192-block kA grid (r12's 64-unit version left half the CUs
// idle on the VALU-heaviest phase). Fragments split 4+4 -> 2-way LDS = free.
static __device__ void ph_xtx(int u, int tid, float* smem,
    const float* __restrict__ x, float* __restrict__ rinv,
    float* __restrict__ Mpart) {
  float* xs  = smem;
  float* rvs = smem + 64 * DIM;
  int row0 = u * 64;
  const float4* xsrc = (const float4*)(x + (size_t)row0 * DIM);
  float4* xdst = (float4*)xs;
  #pragma unroll
  for (int i = 0; i < 8; ++i) xdst[tid + 256 * i] = xsrc[tid + 256 * i];
  __syncthreads();
  int rr = tid >> 2, q = tid & 3;
  const float4* xr = (const float4*)&xs[rr * DIM + q * 32];
  float ss = 0.f;
  #pragma unroll
  for (int i = 0; i < 8; ++i) {
    float4 v = xr[i];
    ss += v.x * v.x + v.y * v.y + v.z * v.z + v.w * v.w;
  }
  ss += __shfl_xor(ss, 1);
  ss += __shfl_xor(ss, 2);
  if (q == 0) { float rv = 1.0f / sqrtf(ss); rvs[rr] = rv; rinv[row0 + rr] = rv; }
  __syncthreads();

  int ty = tid >> 4, tx = tid & 15;
  float acc[8][8];
  #pragma unroll
  for (int i = 0; i < 8; ++i)
    #pragma unroll
    for (int j = 0; j < 8; ++j) acc[i][j] = 0.f;
  #pragma unroll 2
  for (int r = 0; r < 64; ++r) {
    float4 a0 = *(const float4*)&xs[r * DIM + ty * 4];
    float4 a1 = *(const float4*)&xs[r * DIM + 64 + ty * 4];
    float4 b0 = *(const float4*)&xs[r * DIM + tx * 4];
    float4 b1 = *(const float4*)&xs[r * DIM + 64 + tx * 4];
    float rv = rvs[r];
    float a[8] = {a0.x * rv, a0.y * rv, a0.z * rv, a0.w * rv,
                  a1.x * rv, a1.y * rv, a1.z * rv, a1.w * rv};
    float b[8] = {b0.x, b0.y, b0.z, b0.w, b1.x, b1.y, b1.z, b1.w};
    #pragma unroll
    for (int i = 0; i < 8; ++i)
      #pragma unroll
      for (int j = 0; j < 8; ++j) acc[i][j] += a[i] * b[j];
  }
  float* o = Mpart + (size_t)u * (DIM * DIM);
  #pragma unroll
  for (int i = 0; i < 8; ++i) {
    int row = (i < 4) ? (ty * 4 + i) : (64 + ty * 4 + (i - 4));
    *(float4*)&o[row * DIM + tx * 4]      = make_float4(acc[i][0], acc[i][1], acc[i][2], acc[i][3]);
    *(float4*)&o[row * DIM + 64 + tx * 4] = make_float4(acc[i][4], acc[i][5], acc[i][6], acc[i][7]);
  }
}

// hist chunk h (256 thr): LDS histogram; 1 global atomic per TOUCHED bin
// claims the chunk's base; per-edge final slot = base + local rank.
static __device__ void ph_hist(int h, int tid, int* ldeg,
    const int* __restrict__ ei, int* __restrict__ gcnt, int* __restrict__ slot) {
  int4* lz = (int4*)ldeg;
  #pragma unroll
  for (int i = tid; i < NN / 4; i += 256) lz[i] = make_int4(0, 0, 0, 0);
  __syncthreads();
  int e0 = h * HEB + tid * 16;
  int4 c0 = *(const int4*)(ei + NE + e0);       // targets
  int4 c1 = *(const int4*)(ei + NE + e0 + 4);
  int4 c2 = *(const int4*)(ei + NE + e0 + 8);
  int4 c3 = *(const int4*)(ei + NE + e0 + 12);
  int r0  = atomicAdd(&ldeg[c0.x], 1);
  int r1  = atomicAdd(&ldeg[c0.y], 1);
  int r2  = atomicAdd(&ldeg[c0.z], 1);
  int r3  = atomicAdd(&ldeg[c0.w], 1);
  int r4  = atomicAdd(&ldeg[c1.x], 1);
  int r5  = atomicAdd(&ldeg[c1.y], 1);
  int r6  = atomicAdd(&ldeg[c1.z], 1);
  int r7  = atomicAdd(&ldeg[c1.w], 1);
  int r8  = atomicAdd(&ldeg[c2.x], 1);
  int r9  = atomicAdd(&ldeg[c2.y], 1);
  int r10 = atomicAdd(&ldeg[c2.z], 1);
  int r11 = atomicAdd(&ldeg[c2.w], 1);
  int r12 = atomicAdd(&ldeg[c3.x], 1);
  int r13 = atomicAdd(&ldeg[c3.y], 1);
  int r14 = atomicAdd(&ldeg[c3.z], 1);
  int r15 = atomicAdd(&ldeg[c3.w], 1);
  __syncthreads();
  int binb = tid * 32;
  #pragma unroll
  for (int i = 0; i < 8; ++i) {
    int4 v = *(int4*)&ldeg[binb + i * 4];
    if (v.x) ldeg[binb + i * 4 + 0] = atomicAdd(&gcnt[binb + i * 4 + 0], v.x);
    if (v.y) ldeg[binb + i * 4 + 1] = atomicAdd(&gcnt[binb + i * 4 + 1], v.y);
    if (v.z) ldeg[binb + i * 4 + 2] = atomicAdd(&gcnt[binb + i * 4 + 2], v.z);
    if (v.w) ldeg[binb + i * 4 + 3] = atomicAdd(&gcnt[binb + i * 4 + 3], v.w);
  }
  __syncthreads();
  int4 s0 = make_int4(ldeg[c0.x] + r0,  ldeg[c0.y] + r1,  ldeg[c0.z] + r2,  ldeg[c0.w] + r3);
  int4 s1 = make_int4(ldeg[c1.x] + r4,  ldeg[c1.y] + r5,  ldeg[c1.z] + r6,  ldeg[c1.w] + r7);
  int4 s2 = make_int4(ldeg[c2.x] + r8,  ldeg[c2.y] + r9,  ldeg[c2.z] + r10, ldeg[c2.w] + r11);
  int4 s3 = make_int4(ldeg[c3.x] + r12, ldeg[c3.y] + r13, ldeg[c3.z] + r14, ldeg[c3.w] + r15);
  *(int4*)(slot + e0)      = s0;
  *(int4*)(slot + e0 + 4)  = s1;
  *(int4*)(slot + e0 + 8)  = s2;
  *(int4*)(slot + e0 + 12) = s3;
}

// M-reduce unit u (256 thr): sum 128 partials for 64 entries, split-K via LDS
static __device__ void ph_mred(int u, int tid, float* smem,
    const float* __restrict__ Mpart, float* __restrict__ Mmat) {
  int j0 = u * 64;
  int jj = tid & 63, sub = tid >> 6;
  const float* mp = Mpart + (size_t)(sub * 32) * (DIM * DIM) + j0;
  float s = 0.f;
  #pragma unroll 4
  for (int k = 0; k < 32; ++k) s += mp[(size_t)k * (DIM * DIM) + jj];
  smem[sub * 64 + jj] = s;
  __syncthreads();
  if (tid < 64)
    Mmat[j0 + tid] = smem[tid] + smem[64 + tid] + smem[128 + tid] + smem[192 + tid];
}

// scan (256 thr): offs = exclusive scan of gcnt (=deg-1); dis = rsqrt(deg)
static __device__ void ph_scan(int tid, int* wsum,
    const int* __restrict__ gcnt, int* __restrict__ offs, float* __restrict__ dis) {
  int lane = tid & 63, wave = tid >> 6;
  const int4* g4 = (const int4*)gcnt;
  int s = 0;
  #pragma unroll
  for (int i = 0; i < 8; ++i) { int4 v = g4[tid * 8 + i]; s += v.x + v.y + v.z + v.w; }
  int sc = s;
  #pragma unroll
  for (int off = 1; off < 64; off <<= 1) {
    int v = __shfl_up(sc, off);
    if (lane >= off) sc += v;
  }
  if (lane == 63) wsum[wave] = sc;
  __syncthreads();
  if (wave == 0 && lane < 4) {
    int v = wsum[lane];
    #pragma unroll
    for (int off = 1; off < 4; off <<= 1) {
      int u = __shfl_up(v, off);
      if (lane >= off) v += u;
    }
    wsum[lane] = v;
  }
  __syncthreads();
  int run = (wave ? wsum[wave - 1] : 0) + sc - s;
  #pragma unroll
  for (int i = 0; i < 8; ++i) {
    int4 v = g4[tid * 8 + i];
    int4 o;
    o.x = run; run += v.x;
    o.y = run; run += v.y;
    o.z = run; run += v.z;
    o.w = run; run += v.w;
    *(int4*)&offs[tid * 32 + i * 4] = o;
    float4 d;
    d.x = rsqrtf((float)(v.x + 1)); d.y = rsqrtf((float)(v.y + 1));
    d.z = rsqrtf((float)(v.z + 1)); d.w = rsqrtf((float)(v.w + 1));
    *(float4*)&dis[tid * 32 + i * 4] = d;
  }
}

// GEMM unit u (256 thr): RWB=32 rows; thread = 4 rows x 4 cols x {W,M}.
// 256 blocks x 4 waves = 1 wave/SIMD; wv/mv reads 32-addr 2-way = free.
static __device__ void ph_gemm(int u, int tid, float* smem,
    const float* __restrict__ x, const float* __restrict__ W,
    const float* __restrict__ Mmat, const float* __restrict__ rinv,
    const float* __restrict__ dis, unsigned short* __restrict__ xws,
    float* __restrict__ att) {
  float* xs  = smem;                    // 32*132 = 4224 f
  float* Wl  = smem + 4224;             // 2048 f
  float* Ml  = smem + 6272;             // 2048 f
  float* rvs = smem + 8320;             // 32 f
  float* dss = smem + 8352;             // 32 f
  int row0 = u * RWB;
  #pragma unroll
  for (int i = 0; i < 4; ++i) {
    int fidx = i * 256 + tid;           // float4 index 0..1023
    int row = fidx >> 5, c4 = fidx & 31;
    ((float4*)(xs + row * XSS))[c4] =
        ((const float4*)(x + (size_t)(row0 + row) * DIM))[c4];
  }
  if (tid < RWB) { rvs[tid] = rinv[row0 + tid]; dss[tid] = dis[row0 + tid]; }

  int ry = tid >> 5, tx = tid & 31;
  int r0 = ry * 4;
  float4 aw[4], am[4];
  #pragma unroll
  for (int j = 0; j < 4; ++j) { aw[j] = make_float4(0,0,0,0); am[j] = make_float4(0,0,0,0); }

  for (int kk = 0; kk < DIM; kk += BK) {
    __syncthreads();
    const float4* Ws = (const float4*)(W + (size_t)kk * DIM);
    const float4* Ms = (const float4*)(Mmat + (size_t)kk * DIM);
    ((float4*)Wl)[tid]       = Ws[tid];
    ((float4*)Wl)[tid + 256] = Ws[tid + 256];
    ((float4*)Ml)[tid]       = Ms[tid];
    ((float4*)Ml)[tid + 256] = Ms[tid + 256];
    __syncthreads();
    #pragma unroll
    for (int k4 = 0; k4 < BK; k4 += 4) {
      float4 xf[4];
      #pragma unroll
      for (int j = 0; j < 4; ++j)
        xf[j] = *(const float4*)&xs[(r0 + j) * XSS + kk + k4];
      #pragma unroll
      for (int k = 0; k < 4; ++k) {
        float4 wv = *(const float4*)&Wl[(k4 + k) * DIM + tx * 4];
        float4 mv = *(const float4*)&Ml[(k4 + k) * DIM + tx * 4];
        #pragma unroll
        for (int j = 0; j < 4; ++j) {
          float xv = ((const float*)&xf[j])[k];
          aw[j].x += xv * wv.x; aw[j].y += xv * wv.y;
          aw[j].z += xv * wv.z; aw[j].w += xv * wv.w;
          am[j].x += xv * mv.x; am[j].y += xv * mv.y;
          am[j].z += xv * mv.z; am[j].w += xv * mv.w;
        }
      }
    }
  }
  #pragma unroll
  for (int j = 0; j < 4; ++j) {
    int row = row0 + r0 + j;
    float rv = rvs[r0 + j], ds = dss[r0 + j];
    size_t o = (size_t)row * DIM + tx * 4;
    ushort4 wb;
    wb.x = f2bf(aw[j].x * ds); wb.y = f2bf(aw[j].y * ds);
    wb.z = f2bf(aw[j].z * ds); wb.w = f2bf(aw[j].w * ds);
    *(ushort4*)&xws[o] = wb;
    float4 g;
    g.x = 1.0f / (1.0f + __expf(-am[j].x * rv));
    g.y = 1.0f / (1.0f + __expf(-am[j].y * rv));
    g.z = 1.0f / (1.0f + __expf(-am[j].z * rv));
    g.w = 1.0f / (1.0f + __expf(-am[j].w * rv));
    *(float4*)&att[o] = g;
  }
}

// placement chunk u (256 thr): pos = offs[tgt] + slot  (no atomics)
static __device__ void ph_place(int u, int tid,
    const int* __restrict__ ei, const int* __restrict__ offs,
    const int* __restrict__ slot, int* __restrict__ sorted) {
  int e0 = u * PEB + tid * 16;
  #pragma unroll
  for (int i = 0; i < 4; ++i) {
    int4 sv = *(const int4*)(ei + e0 + i * 4);          // sources
    int4 cv = *(const int4*)(ei + NE + e0 + i * 4);     // targets
    int4 sl = *(const int4*)(slot + e0 + i * 4);
    sorted[offs[cv.x] + sl.x] = sv.x;
    sorted[offs[cv.y] + sl.y] = sv.y;
    sorted[offs[cv.z] + sl.z] = sv.z;
    sorted[offs[cv.w] + sl.w] = sv.w;
  }
}

// ==================== kernels ====================
__global__ __launch_bounds__(256) void k_pA(const float* __restrict__ x,
    const int* __restrict__ ei, float* __restrict__ rinv,
    float* __restrict__ Mpart, int* __restrict__ gcnt, int* __restrict__ slot) {
  __shared__ float smem[SMEMF];
  int u = blockIdx.x, tid = threadIdx.x;
  if (u < XB) ph_xtx(u, tid, smem, x, rinv, Mpart);
  else        ph_hist(u - XB, tid, (int*)smem, ei, gcnt, slot);
}
__global__ __launch_bounds__(256) void k_pB(const float* __restrict__ Mpart,
    float* __restrict__ Mmat, const int* __restrict__ gcnt,
    int* __restrict__ offs, float* __restrict__ dis) {
  __shared__ float smem[SMEMF];
  int u = blockIdx.x, tid = threadIdx.x;
  if (u < 256) ph_mred(u, tid, smem, Mpart, Mmat);
  else         ph_scan(tid, (int*)smem, gcnt, offs, dis);
}
__global__ __launch_bounds__(256) void k_pC(const float* __restrict__ x,
    const float* __restrict__ W, const float* __restrict__ Mmat,
    const float* __restrict__ rinv, const float* __restrict__ dis,
    const int* __restrict__ ei, const int* __restrict__ offs,
    const int* __restrict__ slot, int* __restrict__ sorted,
    unsigned short* __restrict__ xws, float* __restrict__ att) {
  __shared__ float smem[SMEMF];
  int u = blockIdx.x, tid = threadIdx.x;
  if (u < NN / RWB) ph_gemm(u, tid, smem, x, W, Mmat, rinv, dis, xws, att);
  else              ph_place(u - NN / RWB, tid, ei, offs, slot, sorted);
}
// gather: one node per 64-thread wave-block; uint (ushort2) loads; unroll 8
__global__ __launch_bounds__(64) void k_pD(const int* __restrict__ offs,
    const int* __restrict__ gcnt, const float* __restrict__ dis,
    const unsigned short* __restrict__ xws, const float* __restrict__ att,
    const float* __restrict__ bias, const int* __restrict__ sorted,
    float* __restrict__ out) {
  int c = blockIdx.x, t = threadIdx.x;
  int base = offs[c];
  int cnt  = gcnt[c];                            // deg-1
  const unsigned int* xw2 = (const unsigned int*)xws;
  unsigned int sv = xw2[(size_t)c * 64 + t];     // self-loop term
  float acc0 = bf2f(sv & 0xffffu), acc1 = bf2f(sv >> 16);
  int k = 0;
  for (; k + 8 <= cnt; k += 8) {
    int4 i0 = *(const int4*)(sorted + base + k);
    int4 i1 = *(const int4*)(sorted + base + k + 4);
    unsigned int v0 = xw2[(size_t)i0.x * 64 + t];
    unsigned int v1 = xw2[(size_t)i0.y * 64 + t];
    unsigned int v2 = xw2[(size_t)i0.z * 64 + t];
    unsigned int v3 = xw2[(size_t)i0.w * 64 + t];
    unsigned int v4 = xw2[(size_t)i1.x * 64 + t];
    unsigned int v5 = xw2[(size_t)i1.y * 64 + t];
    unsigned int v6 = xw2[(size_t)i1.z * 64 + t];
    unsigned int v7 = xw2[(size_t)i1.w * 64 + t];
    acc0 += bf2f(v0 & 0xffffu) + bf2f(v1 & 0xffffu) + bf2f(v2 & 0xffffu) + bf2f(v3 & 0xffffu)
          + bf2f(v4 & 0xffffu) + bf2f(v5 & 0xffffu) + bf2f(v6 & 0xffffu) + bf2f(v7 & 0xffffu);
    acc1 += bf2f(v0 >> 16) + bf2f(v1 >> 16) + bf2f(v2 >> 16) + bf2f(v3 >> 16)
          + bf2f(v4 >> 16) + bf2f(v5 >> 16) + bf2f(v6 >> 16) + bf2f(v7 >> 16);
  }
  for (; k + 4 <= cnt; k += 4) {
    int4 i0 = *(const int4*)(sorted + base + k);
    unsigned int v0 = xw2[(size_t)i0.x * 64 + t];
    unsigned int v1 = xw2[(size_t)i0.y * 64 + t];
    unsigned int v2 = xw2[(size_t)i0.z * 64 + t];
    unsigned int v3 = xw2[(size_t)i0.w * 64 + t];
    acc0 += bf2f(v0 & 0xffffu) + bf2f(v1 & 0xffffu) + bf2f(v2 & 0xffffu) + bf2f(v3 & 0xffffu);
    acc1 += bf2f(v0 >> 16) + bf2f(v1 >> 16) + bf2f(v2 >> 16) + bf2f(v3 >> 16);
  }
  for (; k < cnt; ++k) {
    unsigned int v = xw2[(size_t)sorted[base + k] * 64 + t];
    acc0 += bf2f(v & 0xffffu);
    acc1 += bf2f(v >> 16);
  }
  float dc = dis[c];
  float2 at = ((const float2*)att)[(size_t)c * 64 + t];
  float2 bs = ((const float2*)bias)[t];
  float2 o;
  o.x = (acc0 * dc + bs.x) * at.x;
  o.y = (acc1 * dc + bs.y) * at.y;
  ((float2*)out)[(size_t)c * 64 + t] = o;
}

// ---------------------------------------------------------------------- launch
extern "C" void kernel_launch(void* const* d_in, const int* in_sizes, int n_in,
                              void* d_out, int out_size, void* d_ws, size_t ws_size,
                              hipStream_t stream) {
  const float* x  = (const float*)d_in[0];
  const int*   ei = (const int*)  d_in[1];
  const float* W  = (const float*)d_in[2];
  const float* b  = (const float*)d_in[3];
  float* out = (float*)d_out;

  // ws layout (~15.5 MB)
  unsigned short* xws = (unsigned short*)d_ws;        // NN*DIM bf16
  float* att   = (float*)(xws + (size_t)NN * DIM);    // NN*DIM
  float* Mpart = att + (size_t)NN * DIM;              // XB*DIM*DIM (8 MB)
  float* Mmat  = Mpart + (size_t)XB * DIM * DIM;      // DIM*DIM
  float* rinv  = Mmat + DIM * DIM;                    // NN
  float* dis   = rinv + NN;                           // NN
  int*   gcnt  = (int*)(dis + NN);                    // NN (zeroed below)
  int*   offs  = gcnt + NN;                           // NN
  int*   slot  = offs + NN;                           // NE
  int*   sorted= slot + NE;                           // NE

  hipMemsetAsync(gcnt, 0, NN * sizeof(int), stream);

  k_pA<<<XB + HBH, 256, 0, stream>>>(x, ei, rinv, Mpart, gcnt, slot);
  k_pB<<<257, 256, 0, stream>>>(Mpart, Mmat, gcnt, offs, dis);
  k_pC<<<NN / RWB + PBP, 256, 0, stream>>>(x, W, Mmat, rinv, dis, ei, offs,
                                           slot, sorted, xws, att);
  k_pD<<<NN, 64, 0, stream>>>(offs, gcnt, dis, xws, att, b, sorted, out);
}